// Round 6
// baseline (423.625 us; speedup 1.0000x reference)
//
#include <hip/hip_runtime.h>

// Longformer block, MI355X. B=2 S=2048 E=768 H=12 DH=64 W=256 G=16 FF=3072.
// R5: all dense GEMMs moved to BK=64 (32 MFMA per barrier, half the barrier
// drains of BK=32; LDS 32KB/48KB keeps 3-5 blocks/CU — avoids m132 cliff).

#define BB_ 2
#define SS 2048
#define EE 768
#define HH 12
#define DHH 64
#define GG 16
#define FFN 3072
#define MM (BB_*SS)   // 4096

typedef __bf16 bf16_t;
typedef __bf16 bf16x8_t __attribute__((ext_vector_type(8)));
typedef float f32x4_t __attribute__((ext_vector_type(4)));

// async global->LDS, 16B per lane; lds dest = wave-uniform base + lane*16
__device__ inline void gload16(const void* g, void* l) {
  __builtin_amdgcn_global_load_lds((const __attribute__((address_space(1))) void*)g,
                                   (__attribute__((address_space(3))) void*)l, 16, 0, 0);
}

// ---------------------------------------------------------------------------
// dtype detector (fp32 vs bf16 inputs).
// ---------------------------------------------------------------------------
__global__ __launch_bounds__(64) void detect_kernel(const unsigned int* __restrict__ w,
                                                    int* __restrict__ flag) {
  int cnt = 0;
  for (int i = threadIdx.x; i < 1024; i += 64) {
    unsigned e = (w[i] >> 7) & 0xFF;
    cnt += (e >= 100 && e <= 144) ? 1 : 0;
  }
  for (int off = 32; off; off >>= 1) cnt += __shfl_xor(cnt, off);
  if (threadIdx.x == 0) flag[0] = (cnt > 512) ? 1 : 0;   // 1 = inputs are bf16
}

// ---------------------------------------------------------------------------
// canonicalize x + biases + ln params into bf16.
// ---------------------------------------------------------------------------
struct CanonP { const void* src[11]; bf16_t* dst[11]; };

__global__ __launch_bounds__(256) void canon_kernel(CanonP P, const int* __restrict__ flag) {
  constexpr int ns[11] = {3145728, 768,768,768,768,768,768, 768,768,768,768};
  int idx4 = (blockIdx.x*256 + threadIdx.x)*4;
  const bool isb = flag[0] != 0;
  int off = 0, seg = -1, loc = 0;
  #pragma unroll
  for (int i=0;i<11;i++) {
    if (seg < 0 && idx4 < off + ns[i]) { seg = i; loc = idx4 - off; }
    off += ns[i];
  }
  if (seg < 0) return;
  const void* s = P.src[seg];
  bf16_t* d = P.dst[seg];
  if (isb) {
    *(uint2*)&d[loc] = *(const uint2*)((const unsigned short*)s + loc);
  } else {
    float4 v = *(const float4*)((const float*)s + loc);
    d[loc+0] = (bf16_t)v.x; d[loc+1] = (bf16_t)v.y;
    d[loc+2] = (bf16_t)v.z; d[loc+3] = (bf16_t)v.w;
  }
}

// ---------------------------------------------------------------------------
// transpose + canonicalize: src (R x C) -> dst (C x R, bf16)
// ---------------------------------------------------------------------------
struct TP6 { const void* s[6]; bf16_t* d[6]; };

__global__ __launch_bounds__(256) void trans_kernel(TP6 P, int R, int C,
                                                    const int* __restrict__ flag) {
  const int z = blockIdx.z;
  const void* src = P.s[z]; bf16_t* dst = P.d[z];
  const bool isb = flag[0] != 0;
  __shared__ bf16_t tile[32][33];
  int tx = threadIdx.x & 31, ty = threadIdx.x >> 5;
  int r0 = blockIdx.y*32, c0 = blockIdx.x*32;
  #pragma unroll
  for (int i=0;i<4;i++) {
    int rr = ty + i*8;
    size_t si = (size_t)(r0+rr)*C + c0 + tx;
    tile[rr][tx] = isb ? ((const bf16_t*)src)[si] : (bf16_t)((const float*)src)[si];
  }
  __syncthreads();
  #pragma unroll
  for (int i=0;i<4;i++) {
    int cc = ty + i*8;
    dst[(size_t)(c0+cc)*R + r0 + tx] = tile[tx][cc];
  }
}

__global__ __launch_bounds__(256) void zero_kernel(float* __restrict__ p, int n) {
  int i = blockIdx.x*256 + threadIdx.x;
  if (i < n) p[i] = 0.f;
}

// ---------------------------------------------------------------------------
// flags + rope positions.
// ---------------------------------------------------------------------------
__global__ __launch_bounds__(256) void flags_kernel(const int* __restrict__ am,
                                                    const int* __restrict__ gm,
                                                    float* __restrict__ tpos,
                                                    int* __restrict__ flags) {
  int b = blockIdx.x;
  int t = threadIdx.x;
  int lane = t & 63, wv = t >> 6;
  int base = b*SS + t*8;
  int mg[8]; int isg[8]; int loc = 0;
  for (int i=0;i<8;i++) {
    int a = am[base+i], g = gm[base+i];
    int merged = a*(g+1);
    mg[i] = merged;
    isg[i] = (merged==2) ? 1 : 0;
    loc += isg[i];
  }
  int x = loc;
  for (int off=1; off<64; off<<=1) {
    int y = __shfl_up(x, off);
    if (lane >= off) x += y;
  }
  __shared__ int wtot[4];
  if (lane==63) wtot[wv] = x;
  __syncthreads();
  int prev = 0;
  for (int w=0; w<wv; w++) prev += wtot[w];
  int run = prev + x - loc;
  for (int i=0;i<8;i++) {
    run += isg[i];
    int masked = (mg[i]==0) ? 1 : 0;
    int glob   = (mg[i]==2) ? 1 : 0;
    int rem    = (mg[i]!=1) ? 1 : 0;
    tpos[base+i]  = masked ? 0.f : (float)run;
    flags[base+i] = masked | (glob<<1) | (rem<<2);
  }
}

// ---------------------------------------------------------------------------
// 128x128-tile BK=64 GEMM core. A: M x ldA row-major bf16; BT: N x ldB bf16.
// Per K-step: 8 gload16/lane staging, 32 MFMA/wave (2 k-chunks of 32).
// LDS per tile: 128x64 bf16 = 16KB.
// ---------------------------------------------------------------------------
__device__ inline void gemm128_core(const bf16_t* __restrict__ A,
                                    const bf16_t* __restrict__ BT,
                                    int ldA, int ldB, int kbeg, int kend,
                                    int m0, int n0,
                                    bf16_t* As, bf16_t* Bs,
                                    f32x4_t (&acc)[4][4]) {
  const int t = threadIdx.x;
  const int lane = t & 63, wv = t >> 6;
  const int l15 = lane & 15, quad = lane >> 4;
  const int wr = (wv >> 1) << 6, wc = (wv & 1) << 6;
  const int rsub = lane >> 3, pch = lane & 7;    // staging row-sub / col-chunk
  const size_t abase = (size_t)(m0 + wv*32 + rsub)*ldA + pch*8;
  const size_t bbase = (size_t)(n0 + wv*32 + rsub)*ldB + pch*8;
  bf16_t* lA = As + (wv*32)*64;
  bf16_t* lB = Bs + (wv*32)*64;
  for (int k0 = kbeg; k0 < kend; k0 += 64) {
    __syncthreads();
    #pragma unroll
    for (int j=0;j<4;j++) {
      gload16(A + abase + (size_t)(j*8)*ldA + k0, lA + j*8*64);
      gload16(BT + bbase + (size_t)(j*8)*ldB + k0, lB + j*8*64);
    }
    __syncthreads();
    #pragma unroll
    for (int c=0;c<2;c++) {
      bf16x8_t af[4], bfr[4];
      #pragma unroll
      for (int a=0;a<4;a++) af[a] = *(const bf16x8_t*)&As[(wr + a*16 + l15)*64 + c*32 + quad*8];
      #pragma unroll
      for (int b=0;b<4;b++) bfr[b] = *(const bf16x8_t*)&Bs[(wc + b*16 + l15)*64 + c*32 + quad*8];
      #pragma unroll
      for (int a=0;a<4;a++)
        #pragma unroll
        for (int b=0;b<4;b++)
          acc[a][b] = __builtin_amdgcn_mfma_f32_16x16x32_bf16(af[a], bfr[b], acc[a][b], 0,0,0);
    }
  }
}

// ---------------------------------------------------------------------------
// Fused QKV(+global KV) projection. z: 0=q(scale+rope) 1=k(rope) 2=v 3=kg 4=vg.
// ---------------------------------------------------------------------------
struct ProjParams {
  const bf16_t* W[5];   // transposed [N][K]
  const bf16_t* Bi[5];
  bf16_t* O[5];
};

__global__ __launch_bounds__(256) void proj_kernel(const bf16_t* __restrict__ x,
                                                   ProjParams P,
                                                   const float* __restrict__ tpos) {
  const int m0 = blockIdx.x*128, n0 = blockIdx.y*128;
  const int z  = blockIdx.z;
  __shared__ bf16_t As[128*64];
  __shared__ bf16_t Bs[128*64];
  f32x4_t acc[4][4];
  #pragma unroll
  for (int a=0;a<4;a++)
    #pragma unroll
    for (int b=0;b<4;b++) acc[a][b] = (f32x4_t){0.f,0.f,0.f,0.f};
  gemm128_core(x, P.W[z], EE, EE, 0, EE, m0, n0, As, Bs, acc);

  const int t = threadIdx.x;
  const int lane = t & 63, wv = t >> 6;
  const int l15 = lane & 15, quad = lane >> 4;
  const int wr = (wv >> 1) << 6, wc = (wv & 1) << 6;
  const float scale = (z==0) ? 0.125f : 1.f;
  const bool rope = (z<2);
  const int h = (n0 + wc) >> 6;          // one head per wave half-tile
  bf16_t* Oz = P.O[z];
  const bf16_t* Bz = P.Bi[z];
  float bvals[4];
  #pragma unroll
  for (int b=0;b<4;b++) bvals[b] = (float)Bz[h*64 + b*16 + l15];
  #pragma unroll
  for (int a=0;a<4;a++) {
    #pragma unroll
    for (int r=0;r<4;r++) {
      int row = m0 + wr + a*16 + quad*4 + r;
      int bb = row >> 11, spos = row & (SS-1);
      float vals[4];
      #pragma unroll
      for (int b=0;b<4;b++) vals[b] = (acc[a][b][r] + bvals[b]) * scale;
      if (rope) {
        float tv = tpos[row];
        #pragma unroll
        for (int b=0;b<2;b++) {
          int j = b*16 + l15;                   // freq index in [0,32)
          float inv = __expf(-(float)j * (9.210340371976184f/32.f));
          float ang = tv * inv;
          float sn = __sinf(ang), cs = __cosf(ang);
          float x1 = vals[b], x2 = vals[b+2];
          vals[b]   = x1*cs - x2*sn;
          vals[b+2] = x2*cs + x1*sn;
        }
      }
      bf16_t* dst = Oz + ((size_t)(bb*HH + h)*SS + spos)*DHH;
      #pragma unroll
      for (int b=0;b<4;b++) dst[b*16 + l15] = (bf16_t)vals[b];
    }
  }
}

// ---------------------------------------------------------------------------
// Fused FFN1+FFN3, BK=64: g1 = silu(h0@W1) * (h0@W3). 64 MFMA per barrier.
// LDS 48KB -> 3 blocks/CU if VGPR allows.
// ---------------------------------------------------------------------------
__global__ __launch_bounds__(256) void gemm_ffn13(const bf16_t* __restrict__ A,
                                                  const bf16_t* __restrict__ B1T,
                                                  const bf16_t* __restrict__ B3T,
                                                  bf16_t* __restrict__ g1) {
  const int m0 = blockIdx.x*128, n0 = blockIdx.y*128;
  const int t = threadIdx.x;
  const int lane = t & 63, wv = t >> 6;
  const int l15 = lane & 15, quad = lane >> 4;
  const int wr = (wv >> 1) << 6, wc = (wv & 1) << 6;
  const int rsub = lane >> 3, pch = lane & 7;
  __shared__ bf16_t As[128*64];
  __shared__ bf16_t B1s[128*64];
  __shared__ bf16_t B3s[128*64];
  f32x4_t acc1[4][4], acc3[4][4];
  #pragma unroll
  for (int a=0;a<4;a++)
    #pragma unroll
    for (int b=0;b<4;b++) {
      acc1[a][b] = (f32x4_t){0.f,0.f,0.f,0.f};
      acc3[a][b] = (f32x4_t){0.f,0.f,0.f,0.f};
    }
  const size_t abase = (size_t)(m0 + wv*32 + rsub)*EE + pch*8;
  const size_t bbase = (size_t)(n0 + wv*32 + rsub)*EE + pch*8;
  bf16_t* lA  = As  + (wv*32)*64;
  bf16_t* lB1 = B1s + (wv*32)*64;
  bf16_t* lB3 = B3s + (wv*32)*64;
  for (int k0 = 0; k0 < EE; k0 += 64) {
    __syncthreads();
    #pragma unroll
    for (int j=0;j<4;j++) {
      gload16(A   + abase + (size_t)(j*8)*EE + k0, lA  + j*8*64);
      gload16(B1T + bbase + (size_t)(j*8)*EE + k0, lB1 + j*8*64);
      gload16(B3T + bbase + (size_t)(j*8)*EE + k0, lB3 + j*8*64);
    }
    __syncthreads();
    #pragma unroll
    for (int c=0;c<2;c++) {
      bf16x8_t af[4], b1f[4], b3f[4];
      #pragma unroll
      for (int a=0;a<4;a++) af[a] = *(const bf16x8_t*)&As[(wr + a*16 + l15)*64 + c*32 + quad*8];
      #pragma unroll
      for (int b=0;b<4;b++) {
        b1f[b] = *(const bf16x8_t*)&B1s[(wc + b*16 + l15)*64 + c*32 + quad*8];
        b3f[b] = *(const bf16x8_t*)&B3s[(wc + b*16 + l15)*64 + c*32 + quad*8];
      }
      #pragma unroll
      for (int a=0;a<4;a++)
        #pragma unroll
        for (int b=0;b<4;b++) {
          acc1[a][b] = __builtin_amdgcn_mfma_f32_16x16x32_bf16(af[a], b1f[b], acc1[a][b], 0,0,0);
          acc3[a][b] = __builtin_amdgcn_mfma_f32_16x16x32_bf16(af[a], b3f[b], acc3[a][b], 0,0,0);
        }
    }
  }
  #pragma unroll
  for (int a=0;a<4;a++)
    #pragma unroll
    for (int r=0;r<4;r++) {
      int row = m0 + wr + a*16 + quad*4 + r;
      #pragma unroll
      for (int b=0;b<4;b++) {
        float a1 = acc1[a][b][r];
        float sil = a1 / (1.f + __expf(-a1));
        g1[(size_t)row*FFN + n0 + wc + b*16 + l15] = (bf16_t)(sil * acc3[a][b][r]);
      }
    }
}

// ---------------------------------------------------------------------------
// FFN down, split-K=4: partial z covers K in [z*768,(z+1)*768) -> Pz (fp32).
// ---------------------------------------------------------------------------
struct Ffn2Out { float* p[4]; };

__global__ __launch_bounds__(256) void gemm_ffn2(const bf16_t* __restrict__ A,
                                                 const bf16_t* __restrict__ BT,
                                                 Ffn2Out O) {
  const int m0 = blockIdx.x*128, n0 = blockIdx.y*128;
  const int kz = blockIdx.z;
  __shared__ bf16_t As[128*64];
  __shared__ bf16_t Bs[128*64];
  f32x4_t acc[4][4];
  #pragma unroll
  for (int a=0;a<4;a++)
    #pragma unroll
    for (int b=0;b<4;b++) acc[a][b] = (f32x4_t){0.f,0.f,0.f,0.f};
  gemm128_core(A, BT, FFN, FFN, kz*768, (kz+1)*768, m0, n0, As, Bs, acc);
  const int t = threadIdx.x;
  const int lane = t & 63, wv = t >> 6;
  const int l15 = lane & 15, quad = lane >> 4;
  const int wr = (wv >> 1) << 6, wc = (wv & 1) << 6;
  float* C = O.p[kz];
  #pragma unroll
  for (int a=0;a<4;a++)
    #pragma unroll
    for (int r=0;r<4;r++) {
      int row = m0 + wr + a*16 + quad*4 + r;
      #pragma unroll
      for (int b=0;b<4;b++)
        C[(size_t)row*EE + n0 + wc + b*16 + l15] = acc[a][b][r];
    }
}

// ---------------------------------------------------------------------------
// gq projection (16 rows/batch).
// ---------------------------------------------------------------------------
__global__ __launch_bounds__(64) void qg_kernel(const bf16_t* __restrict__ x,
                                                const bf16_t* __restrict__ WqgT,
                                                const bf16_t* __restrict__ bqg,
                                                float* __restrict__ qgb) {
  int g = blockIdx.x, h = blockIdx.y, b = blockIdx.z;
  int d = threadIdx.x;
  __shared__ float xs[EE];
  for (int i=d; i<EE; i+=64) xs[i] = (float)x[((size_t)b*SS + g)*EE + i];
  __syncthreads();
  float acc = 0.f;
  const bf16_t* wrow = WqgT + (size_t)(h*64+d)*EE;
  for (int k=0;k<EE;k++) acc += xs[k] * (float)wrow[k];
  acc = (acc + (float)bqg[h*64+d]) * 0.125f;
  qgb[((size_t)(b*HH+h)*GG + g)*DHH + d] = acc;
}

// ---------------------------------------------------------------------------
// Band (sliding-window) attention + global-key columns, MFMA.
// ---------------------------------------------------------------------------
__global__ __launch_bounds__(256) void band_kernel(const bf16_t* __restrict__ qb,
                                                   const bf16_t* __restrict__ kb,
                                                   const bf16_t* __restrict__ vb,
                                                   const int* __restrict__ flags,
                                                   float* __restrict__ attn) {
  const int p0 = blockIdx.x*64;
  const int h = blockIdx.y, b = blockIdx.z;
  const int t = threadIdx.x;
  const int wv = t>>6, lane = t&63;
  const int l15 = lane & 15, quad = lane >> 4;
  const size_t bh = (size_t)(b*HH+h);
  const bf16_t* kbh = kb + bh*SS*DHH;
  const bf16_t* vbh = vb + bh*SS*DHH;
  const int* fl = flags + b*SS;
  const int q0 = p0 + wv*16;

  __shared__ bf16_t Vt[64*72];          // [dh][key]
  __shared__ bf16_t Pw[4][16*72];       // per-wave P [q][key]

  const bf16_t* qrow = qb + (bh*SS + q0 + l15)*DHH;
  bf16x8_t qa0 = *(const bf16x8_t*)(qrow + quad*8);
  bf16x8_t qa1 = *(const bf16x8_t*)(qrow + 32 + quad*8);

  f32x4_t o[4];
  #pragma unroll
  for (int i=0;i<4;i++) o[i] = (f32x4_t){0.f,0.f,0.f,0.f};
  float lsum[4] = {0.f,0.f,0.f,0.f};
  bf16_t* P = Pw[wv];

  for (int unit=0; unit<10; unit++) {
    const int kb0 = (unit<9) ? (p0 - 256 + unit*64) : 0;
    __syncthreads();
    {
      int kp  = (t & 31)*2;
      int dh0 = (t >> 5)*8;
      int k1 = kb0 + kp, k2 = kb0 + kp + 1;
      int kc1 = min(max(k1,0),SS-1), kc2 = min(max(k2,0),SS-1);
      bf16x8_t v1 = *(const bf16x8_t*)(vbh + (size_t)kc1*DHH + dh0);
      bf16x8_t v2 = *(const bf16x8_t*)(vbh + (size_t)kc2*DHH + dh0);
      #pragma unroll
      for (int i=0;i<8;i++) {
        union { unsigned u; bf16_t hh[2]; } pk;
        pk.hh[0] = v1[i]; pk.hh[1] = v2[i];
        *(unsigned*)&Vt[(dh0+i)*72 + kp] = pk.u;
      }
    }
    __syncthreads();
    const int nsub = (unit<9) ? 4 : 1;
    for (int sub=0; sub<4; sub++) {
      if (sub < nsub) {
        int kpos = kb0 + sub*16 + l15;
        int kc = min(max(kpos,0),SS-1);
        const bf16_t* krow = kbh + (size_t)kc*DHH;
        bf16x8_t kf0 = *(const bf16x8_t*)(krow + quad*8);
        bf16x8_t kf1 = *(const bf16x8_t*)(krow + 32 + quad*8);
        f32x4_t s = (f32x4_t){0.f,0.f,0.f,0.f};
        s = __builtin_amdgcn_mfma_f32_16x16x32_bf16(qa0, kf0, s, 0,0,0);
        s = __builtin_amdgcn_mfma_f32_16x16x32_bf16(qa1, kf1, s, 0,0,0);
        bool drop = false;
        if (unit<9) drop = (kpos<0) || (kpos>=SS) || (((fl[kc]>>2)&1)!=0);
        #pragma unroll
        for (int r=0;r<4;r++) {
          float e;
          if (unit==9) {
            e = __expf(s[r]);
          } else {
            int dj = kpos - (q0 + quad*4 + r);
            bool valid = (dj>=-256) && (dj<=256) && (!drop);
            e = valid ? __expf(s[r]) : 0.f;
          }
          lsum[r] += e;
          P[(quad*4+r)*72 + sub*16 + l15] = (bf16_t)e;
        }
      } else {
        #pragma unroll
        for (int r=0;r<4;r++) P[(quad*4+r)*72 + sub*16 + l15] = (bf16_t)0.f;
      }
    }
    #pragma unroll
    for (int chunk=0; chunk<2; chunk++) {
      bf16x8_t pf = *(const bf16x8_t*)&P[l15*72 + chunk*32 + quad*8];
      #pragma unroll
      for (int nt=0; nt<4; nt++) {
        bf16x8_t vf = *(const bf16x8_t*)&Vt[(nt*16+l15)*72 + chunk*32 + quad*8];
        o[nt] = __builtin_amdgcn_mfma_f32_16x16x32_bf16(pf, vf, o[nt], 0,0,0);
      }
    }
  }
  #pragma unroll
  for (int r=0;r<4;r++) {
    float s = lsum[r];
    s += __shfl_xor(s,1); s += __shfl_xor(s,2);
    s += __shfl_xor(s,4); s += __shfl_xor(s,8);
    lsum[r] = s;
  }
  #pragma unroll
  for (int r=0;r<4;r++) {
    int q = q0 + quad*4 + r;
    int masked = fl[q] & 1;
    float inv = masked ? 0.f : 1.f/lsum[r];
    float* dst = attn + ((size_t)(b*SS+q))*EE + h*64 + l15;
    #pragma unroll
    for (int nt=0; nt<4; nt++) dst[nt*16] = o[nt][r]*inv;
  }
}

// ---------------------------------------------------------------------------
// Global attention, key-split partials + finalize.
// ---------------------------------------------------------------------------
__global__ __launch_bounds__(256) void gattn_part(const float* __restrict__ qgb,
                                                  const bf16_t* __restrict__ kgb,
                                                  const bf16_t* __restrict__ vgb,
                                                  const int* __restrict__ flags,
                                                  float* __restrict__ go,
                                                  float* __restrict__ gl) {
  const int kbase = blockIdx.x*128;
  const int h = blockIdx.y, b = blockIdx.z;
  const int t = threadIdx.x;
  __shared__ float gqs[16*68];
  __shared__ float Ks[64*68];
  __shared__ float Vs[64*68];
  __shared__ float es[16*64];
  const size_t bh = (size_t)(b*HH+h);
  #pragma unroll
  for (int j=0;j<4;j++) {
    int idx = t + j*256;
    int g = idx>>6, d = idx&63;
    gqs[g*68+d] = qgb[(bh*GG + g)*DHH + d];
  }
  float accv[4] = {0.f,0.f,0.f,0.f};
  float lpart = 0.f;
  const int gs = t>>4, kslot = t&15;
  const int dp = t&63, grp = t>>6;
  const bf16_t* kb_ = kgb + bh*SS*DHH;
  const bf16_t* vb_ = vgb + bh*SS*DHH;
  const int* fl = flags + b*SS;
  for (int tile=0; tile<2; tile++) {
    int k0 = kbase + tile*64;
    __syncthreads();
    {
      int row = t>>2, seg = t&3;
      const bf16_t* sk = kb_ + (size_t)(k0+row)*DHH + seg*16;
      const bf16_t* sv = vb_ + (size_t)(k0+row)*DHH + seg*16;
      bf16x8_t k1 = *(const bf16x8_t*)sk;
      bf16x8_t k2 = *(const bf16x8_t*)(sk+8);
      bf16x8_t v1 = *(const bf16x8_t*)sv;
      bf16x8_t v2 = *(const bf16x8_t*)(sv+8);
      #pragma unroll
      for (int i=0;i<8;i++) {
        Ks[row*68 + seg*16 + i]     = (float)k1[i];
        Ks[row*68 + seg*16 + 8 + i] = (float)k2[i];
        Vs[row*68 + seg*16 + i]     = (float)v1[i];
        Vs[row*68 + seg*16 + 8 + i] = (float)v2[i];
      }
    }
    __syncthreads();
    #pragma unroll
    for (int j=0;j<4;j++) {
      int key = kslot + 16*j;
      const float* gq = &gqs[gs*68];
      const float* kr = &Ks[key*68];
      float s = 0.f;
      #pragma unroll
      for (int d4=0; d4<64; d4+=4) {
        float4 a = *(const float4*)(gq + d4);
        float4 kk = *(const float4*)(kr + d4);
        s += a.x*kk.x + a.y*kk.y + a.z*kk.z + a.w*kk.w;
      }
      int msk = fl[k0+key] & 1;
      float e = msk ? 0.f : __expf(s);
      es[gs*64+key] = e;
      lpart += e;
    }
    __syncthreads();
    #pragma unroll
    for (int g=0; g<4; g++) {
      int gg = grp*4+g;
      float a = accv[g];
      for (int key=0;key<64;key++) a += es[gg*64+key]*Vs[key*68+dp];
      accv[g] = a;
    }
  }
  __syncthreads();
  es[gs*64 + kslot] = lpart;
  __syncthreads();
  if (t < 16) {
    float s = 0.f;
    for (int j=0;j<16;j++) s += es[t*64+j];
    atomicAdd(&gl[bh*16 + t], s);
  }
  #pragma unroll
  for (int g=0; g<4; g++)
    atomicAdd(&go[(bh*16 + grp*4+g)*64 + dp], accv[g]);
}

__global__ __launch_bounds__(256) void gattn_fin(const float* __restrict__ go,
                                                 const float* __restrict__ gl,
                                                 float* __restrict__ attn) {
  int idx = blockIdx.x*256 + threadIdx.x;        // < B*H*16*64 = 24576
  int dp = idx & 63;
  int g  = (idx >> 6) & 15;
  int h  = (idx >> 10) % HH;
  int b  = idx / (1024*HH);
  attn[((size_t)b*SS + g)*EE + h*64 + dp] = go[idx] / gl[idx>>6];
}

// ---------------------------------------------------------------------------
// Residual add + LayerNorm. B-side = sum of up to 4 fp32 partials.
// ---------------------------------------------------------------------------
__global__ __launch_bounds__(256) void addln_kernel(const bf16_t* __restrict__ Abf,
                                                    const float* __restrict__ Af,
                                                    const float* __restrict__ B0,
                                                    const float* __restrict__ B1,
                                                    const float* __restrict__ B2,
                                                    const float* __restrict__ B3,
                                                    const bf16_t* __restrict__ gw,
                                                    const bf16_t* __restrict__ bw,
                                                    float* __restrict__ outf,
                                                    bf16_t* __restrict__ outb,
                                                    const int* __restrict__ flagp) {
  int r = blockIdx.x, t = threadIdx.x;
  int lane = t&63, wv = t>>6;
  float v[3]; float sum=0.f, ss=0.f;
  #pragma unroll
  for (int j=0;j<3;j++) {
    int idx = t + j*256;
    size_t gi = (size_t)r*EE+idx;
    float a = Abf ? (float)Abf[gi] : Af[gi];
    float val = a + B0[gi];
    if (B1) val += B1[gi] + B2[gi] + B3[gi];
    v[j] = val; sum += val; ss += val*val;
  }
  #pragma unroll
  for (int off=32; off>=1; off>>=1) {
    sum += __shfl_xor(sum, off);
    ss  += __shfl_xor(ss, off);
  }
  __shared__ float s1[4], s2[4];
  if (lane==0) { s1[wv]=sum; s2[wv]=ss; }
  __syncthreads();
  sum = s1[0]+s1[1]+s1[2]+s1[3];
  ss  = s2[0]+s2[1]+s2[2]+s2[3];
  float mean = sum * (1.f/(float)EE);
  float var  = ss * (1.f/(float)EE) - mean*mean;
  float rstd = rsqrtf(var + 1e-5f);
  bool wantb, wantf;
  if (flagp) { bool isb = (*flagp)!=0; wantb = isb; wantf = !isb; }
  else { wantb = (outb!=nullptr); wantf = (outf!=nullptr); }
  #pragma unroll
  for (int j=0;j<3;j++) {
    int idx = t + j*256;
    float o = (v[j]-mean)*rstd*(float)gw[idx] + (float)bw[idx];
    if (wantf) outf[(size_t)r*EE+idx] = o;
    if (wantb) outb[(size_t)r*EE+idx] = (bf16_t)o;
  }
}

// ---------------------------------------------------------------------------
extern "C" void kernel_launch(void* const* d_in, const int* in_sizes, int n_in,
                              void* d_out, int out_size, void* d_ws, size_t ws_size,
                              hipStream_t stream) {
  const void* x_r    = d_in[0];
  const int* am      = (const int*)d_in[1];
  const int* gm      = (const int*)d_in[2];
  (void)in_sizes; (void)n_in; (void)out_size; (void)ws_size;

  char* ws = (char*)d_ws;
  size_t off = 0;
  auto alloc = [&](size_t bytes) -> void* {
    void* p = ws + off;
    off += (bytes + 255) & ~(size_t)255;
    return p;
  };
  // canonical bf16 tensors (weights transposed to [N][K])
  bf16_t* xc    = (bf16_t*)alloc((size_t)MM*EE*2);
  bf16_t* WT[6]; bf16_t* bc[6];
  for (int i=0;i<6;i++) { WT[i] = (bf16_t*)alloc((size_t)EE*EE*2); bc[i] = (bf16_t*)alloc(EE*2); }
  bf16_t* lnc[4];
  for (int i=0;i<4;i++) lnc[i] = (bf16_t*)alloc(EE*2);
  bf16_t* W1T = (bf16_t*)alloc((size_t)EE*FFN*2);
  bf16_t* W3T = (bf16_t*)alloc((size_t)EE*FFN*2);
  bf16_t* W2T = (bf16_t*)alloc((size_t)FFN*EE*2);
  // intermediates
  const size_t NBHSD = (size_t)BB_*HH*SS*DHH;
  bf16_t* qb    = (bf16_t*)alloc(NBHSD*2);
  bf16_t* kb    = (bf16_t*)alloc(NBHSD*2);
  bf16_t* vb    = (bf16_t*)alloc(NBHSD*2);
  bf16_t* kgb   = (bf16_t*)alloc(NBHSD*2);
  bf16_t* vgb   = (bf16_t*)alloc(NBHSD*2);
  float* qgb   = (float*)alloc((size_t)BB_*HH*GG*DHH*4);
  float* attn  = (float*)alloc((size_t)MM*EE*4);    // reused as ffn2 partial 0
  float* h0f   = (float*)alloc((size_t)MM*EE*4);
  bf16_t* h0b  = (bf16_t*)alloc((size_t)MM*EE*2);
  bf16_t* g1   = (bf16_t*)alloc((size_t)MM*FFN*2);
  float* p3    = (float*)alloc((size_t)MM*EE*4);    // ffn2 partial 3
  float* go    = (float*)alloc((size_t)BB_*HH*GG*DHH*4);  // 24576 f32
  float* gl    = (float*)alloc((size_t)BB_*HH*GG*4);      // 384 f32 (contiguous)
  float* tposb = (float*)alloc((size_t)BB_*SS*4);
  int*   flagb = (int*)alloc((size_t)BB_*SS*4);
  int*   dflag = (int*)alloc(256);
  // ffn2 partials 1/2 alias the q/k/v region (dead before ffn2; 25.2MB <= 31.5MB)
  float* p1 = (float*)qb;
  float* p2 = (float*)qb + (size_t)MM*EE;

  // 0. dtype detect on Wq
  detect_kernel<<<1, 64, 0, stream>>>((const unsigned int*)d_in[3], dflag);

  // 1. canonicalize x + biases + ln
  CanonP CP;
  const void* csrc[11] = { x_r, d_in[4], d_in[6], d_in[8], d_in[10], d_in[12], d_in[14],
                           d_in[15], d_in[16], d_in[17], d_in[18] };
  bf16_t* cdst[11] = { xc, bc[0], bc[1], bc[2], bc[3], bc[4], bc[5],
                       lnc[0], lnc[1], lnc[2], lnc[3] };
  for (int i=0;i<11;i++) { CP.src[i]=csrc[i]; CP.dst[i]=cdst[i]; }
  canon_kernel<<<3081, 256, 0, stream>>>(CP, dflag);

  // 2. transpose-canonicalize weights
  TP6 T6;
  const int wi[6] = {3,5,7,9,11,13};                 // Wq Wk Wv Wqg Wkg Wvg
  for (int i=0;i<6;i++) { T6.s[i]=d_in[wi[i]]; T6.d[i]=WT[i]; }
  trans_kernel<<<dim3(24,24,6), 256, 0, stream>>>(T6, EE, EE, dflag);
  TP6 TF; TF.s[0]=d_in[19]; TF.d[0]=W1T; TF.s[1]=d_in[20]; TF.d[1]=W3T;
  for (int i=2;i<6;i++) { TF.s[i]=d_in[19]; TF.d[i]=W1T; }
  trans_kernel<<<dim3(96,24,2), 256, 0, stream>>>(TF, EE, FFN, dflag);
  TP6 T2; T2.s[0]=d_in[21]; T2.d[0]=W2T;
  for (int i=1;i<6;i++) { T2.s[i]=d_in[21]; T2.d[i]=W2T; }
  trans_kernel<<<dim3(24,96,1), 256, 0, stream>>>(T2, FFN, EE, dflag);

  // 3. zero global-attn accumulators (go+gl contiguous: 24960 floats)
  zero_kernel<<<98, 256, 0, stream>>>(go, 24960);

  // 4. mask flags + rope positions
  flags_kernel<<<BB_, 256, 0, stream>>>(am, gm, tposb, flagb);

  // 5. fused projections (q,k,v,kg,vg)
  ProjParams P;
  P.W[0]=WT[0]; P.Bi[0]=bc[0]; P.O[0]=qb;
  P.W[1]=WT[1]; P.Bi[1]=bc[1]; P.O[1]=kb;
  P.W[2]=WT[2]; P.Bi[2]=bc[2]; P.O[2]=vb;
  P.W[3]=WT[4]; P.Bi[3]=bc[4]; P.O[3]=kgb;   // Wkg
  P.W[4]=WT[5]; P.Bi[4]=bc[5]; P.O[4]=vgb;   // Wvg
  proj_kernel<<<dim3(MM/128, EE/128, 5), 256, 0, stream>>>(xc, P, tposb);

  // 6. gq (first G rows per batch)
  qg_kernel<<<dim3(GG, HH, BB_), 64, 0, stream>>>(xc, WT[3], bc[3], qgb);

  // 7. band + global-column attention -> attn
  band_kernel<<<dim3(SS/64, HH, BB_), 256, 0, stream>>>(qb, kb, vb, flagb, attn);

  // 8. global-attention rows (key-split partials + finalize)
  gattn_part<<<dim3(SS/128, HH, BB_), 256, 0, stream>>>(qgb, kgb, vgb, flagb, go, gl);
  gattn_fin<<<96, 256, 0, stream>>>(go, gl, attn);

  // 9. h0 = LN(x + attn)
  addln_kernel<<<MM, 256, 0, stream>>>(xc, nullptr, attn, nullptr, nullptr, nullptr,
                                       lnc[0], lnc[1], h0f, h0b, nullptr);

  // 10. FFN: fused gate (BK=64), then split-K down-proj
  gemm_ffn13<<<dim3(MM/128, FFN/128), 256, 0, stream>>>(h0b, W1T, W3T, g1);
  Ffn2Out FO; FO.p[0]=attn; FO.p[1]=p1; FO.p[2]=p2; FO.p[3]=p3;
  gemm_ffn2<<<dim3(MM/128, EE/128, 4), 256, 0, stream>>>(g1, W2T, FO);

  // 11. out = LN(h0 + sum of ffn partials) -> fp32 or bf16 per detected dtype
  addln_kernel<<<MM, 256, 0, stream>>>(nullptr, h0f, attn, p1, p2, p3,
                                       lnc[2], lnc[3],
                                       (float*)d_out, (bf16_t*)d_out, dflag);
}

// Round 7
// 398.394 us; speedup vs baseline: 1.0633x; 1.0633x over previous
//
#include <hip/hip_runtime.h>

// Longformer block, MI355X. B=2 S=2048 E=768 H=12 DH=64 W=256 G=16 FF=3072.
// R6: XOR chunk-swizzle on all BK=64 GEMM LDS tiles. BK=64 row stride is
// 128B = exactly 32 banks, so unswizzled frag reads were 16-way conflicts
// (10.6M SQ_LDS_BANK_CONFLICT on ffn13). Swizzle: LDS pos p of row r holds
// global chunk p^(r&7); staging lane (rsub,pch) loads chunk pch^rsub.

#define BB_ 2
#define SS 2048
#define EE 768
#define HH 12
#define DHH 64
#define GG 16
#define FFN 3072
#define MM (BB_*SS)   // 4096

typedef __bf16 bf16_t;
typedef __bf16 bf16x8_t __attribute__((ext_vector_type(8)));
typedef float f32x4_t __attribute__((ext_vector_type(4)));

// async global->LDS, 16B per lane; lds dest = wave-uniform base + lane*16
__device__ inline void gload16(const void* g, void* l) {
  __builtin_amdgcn_global_load_lds((const __attribute__((address_space(1))) void*)g,
                                   (__attribute__((address_space(3))) void*)l, 16, 0, 0);
}

// ---------------------------------------------------------------------------
// dtype detector (fp32 vs bf16 inputs).
// ---------------------------------------------------------------------------
__global__ __launch_bounds__(64) void detect_kernel(const unsigned int* __restrict__ w,
                                                    int* __restrict__ flag) {
  int cnt = 0;
  for (int i = threadIdx.x; i < 1024; i += 64) {
    unsigned e = (w[i] >> 7) & 0xFF;
    cnt += (e >= 100 && e <= 144) ? 1 : 0;
  }
  for (int off = 32; off; off >>= 1) cnt += __shfl_xor(cnt, off);
  if (threadIdx.x == 0) flag[0] = (cnt > 512) ? 1 : 0;   // 1 = inputs are bf16
}

// ---------------------------------------------------------------------------
// canonicalize x + biases + ln params into bf16.
// ---------------------------------------------------------------------------
struct CanonP { const void* src[11]; bf16_t* dst[11]; };

__global__ __launch_bounds__(256) void canon_kernel(CanonP P, const int* __restrict__ flag) {
  constexpr int ns[11] = {3145728, 768,768,768,768,768,768, 768,768,768,768};
  int idx4 = (blockIdx.x*256 + threadIdx.x)*4;
  const bool isb = flag[0] != 0;
  int off = 0, seg = -1, loc = 0;
  #pragma unroll
  for (int i=0;i<11;i++) {
    if (seg < 0 && idx4 < off + ns[i]) { seg = i; loc = idx4 - off; }
    off += ns[i];
  }
  if (seg < 0) return;
  const void* s = P.src[seg];
  bf16_t* d = P.dst[seg];
  if (isb) {
    *(uint2*)&d[loc] = *(const uint2*)((const unsigned short*)s + loc);
  } else {
    float4 v = *(const float4*)((const float*)s + loc);
    d[loc+0] = (bf16_t)v.x; d[loc+1] = (bf16_t)v.y;
    d[loc+2] = (bf16_t)v.z; d[loc+3] = (bf16_t)v.w;
  }
}

// ---------------------------------------------------------------------------
// transpose + canonicalize: src (R x C) -> dst (C x R, bf16)
// ---------------------------------------------------------------------------
struct TP6 { const void* s[6]; bf16_t* d[6]; };

__global__ __launch_bounds__(256) void trans_kernel(TP6 P, int R, int C,
                                                    const int* __restrict__ flag) {
  const int z = blockIdx.z;
  const void* src = P.s[z]; bf16_t* dst = P.d[z];
  const bool isb = flag[0] != 0;
  __shared__ bf16_t tile[32][33];
  int tx = threadIdx.x & 31, ty = threadIdx.x >> 5;
  int r0 = blockIdx.y*32, c0 = blockIdx.x*32;
  #pragma unroll
  for (int i=0;i<4;i++) {
    int rr = ty + i*8;
    size_t si = (size_t)(r0+rr)*C + c0 + tx;
    tile[rr][tx] = isb ? ((const bf16_t*)src)[si] : (bf16_t)((const float*)src)[si];
  }
  __syncthreads();
  #pragma unroll
  for (int i=0;i<4;i++) {
    int cc = ty + i*8;
    dst[(size_t)(c0+cc)*R + r0 + tx] = tile[tx][cc];
  }
}

__global__ __launch_bounds__(256) void zero_kernel(float* __restrict__ p, int n) {
  int i = blockIdx.x*256 + threadIdx.x;
  if (i < n) p[i] = 0.f;
}

// ---------------------------------------------------------------------------
// flags + rope positions.
// ---------------------------------------------------------------------------
__global__ __launch_bounds__(256) void flags_kernel(const int* __restrict__ am,
                                                    const int* __restrict__ gm,
                                                    float* __restrict__ tpos,
                                                    int* __restrict__ flags) {
  int b = blockIdx.x;
  int t = threadIdx.x;
  int lane = t & 63, wv = t >> 6;
  int base = b*SS + t*8;
  int mg[8]; int isg[8]; int loc = 0;
  for (int i=0;i<8;i++) {
    int a = am[base+i], g = gm[base+i];
    int merged = a*(g+1);
    mg[i] = merged;
    isg[i] = (merged==2) ? 1 : 0;
    loc += isg[i];
  }
  int x = loc;
  for (int off=1; off<64; off<<=1) {
    int y = __shfl_up(x, off);
    if (lane >= off) x += y;
  }
  __shared__ int wtot[4];
  if (lane==63) wtot[wv] = x;
  __syncthreads();
  int prev = 0;
  for (int w=0; w<wv; w++) prev += wtot[w];
  int run = prev + x - loc;
  for (int i=0;i<8;i++) {
    run += isg[i];
    int masked = (mg[i]==0) ? 1 : 0;
    int glob   = (mg[i]==2) ? 1 : 0;
    int rem    = (mg[i]!=1) ? 1 : 0;
    tpos[base+i]  = masked ? 0.f : (float)run;
    flags[base+i] = masked | (glob<<1) | (rem<<2);
  }
}

// ---------------------------------------------------------------------------
// 128x128-tile BK=64 GEMM core with XOR chunk swizzle.
// LDS row r (stride 64 elems), 16B-chunk position p holds global chunk p^(r&7).
// ---------------------------------------------------------------------------
__device__ inline void gemm128_core(const bf16_t* __restrict__ A,
                                    const bf16_t* __restrict__ BT,
                                    int ldA, int ldB, int kbeg, int kend,
                                    int m0, int n0,
                                    bf16_t* As, bf16_t* Bs,
                                    f32x4_t (&acc)[4][4]) {
  const int t = threadIdx.x;
  const int lane = t & 63, wv = t >> 6;
  const int l15 = lane & 15, quad = lane >> 4;
  const int wr = (wv >> 1) << 6, wc = (wv & 1) << 6;
  const int rsub = lane >> 3, pch = lane & 7;    // staging row-sub / chunk pos
  const int sch = pch ^ rsub;                    // swizzled source chunk
  const size_t abase = (size_t)(m0 + wv*32 + rsub)*ldA + sch*8;
  const size_t bbase = (size_t)(n0 + wv*32 + rsub)*ldB + sch*8;
  const int sx = l15 & 7;                        // read-side swizzle
  bf16_t* lA = As + (wv*32)*64;
  bf16_t* lB = Bs + (wv*32)*64;
  for (int k0 = kbeg; k0 < kend; k0 += 64) {
    __syncthreads();
    #pragma unroll
    for (int j=0;j<4;j++) {
      gload16(A + abase + (size_t)(j*8)*ldA + k0, lA + j*8*64);
      gload16(BT + bbase + (size_t)(j*8)*ldB + k0, lB + j*8*64);
    }
    __syncthreads();
    #pragma unroll
    for (int c=0;c<2;c++) {
      bf16x8_t af[4], bfr[4];
      #pragma unroll
      for (int a=0;a<4;a++)
        af[a] = *(const bf16x8_t*)&As[(wr + a*16 + l15)*64 + ((c*4+quad)^sx)*8];
      #pragma unroll
      for (int b=0;b<4;b++)
        bfr[b] = *(const bf16x8_t*)&Bs[(wc + b*16 + l15)*64 + ((c*4+quad)^sx)*8];
      #pragma unroll
      for (int a=0;a<4;a++)
        #pragma unroll
        for (int b=0;b<4;b++)
          acc[a][b] = __builtin_amdgcn_mfma_f32_16x16x32_bf16(af[a], bfr[b], acc[a][b], 0,0,0);
    }
  }
}

// ---------------------------------------------------------------------------
// Fused QKV(+global KV) projection. z: 0=q(scale+rope) 1=k(rope) 2=v 3=kg 4=vg.
// ---------------------------------------------------------------------------
struct ProjParams {
  const bf16_t* W[5];   // transposed [N][K]
  const bf16_t* Bi[5];
  bf16_t* O[5];
};

__global__ __launch_bounds__(256) void proj_kernel(const bf16_t* __restrict__ x,
                                                   ProjParams P,
                                                   const float* __restrict__ tpos) {
  const int m0 = blockIdx.x*128, n0 = blockIdx.y*128;
  const int z  = blockIdx.z;
  __shared__ bf16_t As[128*64];
  __shared__ bf16_t Bs[128*64];
  f32x4_t acc[4][4];
  #pragma unroll
  for (int a=0;a<4;a++)
    #pragma unroll
    for (int b=0;b<4;b++) acc[a][b] = (f32x4_t){0.f,0.f,0.f,0.f};
  gemm128_core(x, P.W[z], EE, EE, 0, EE, m0, n0, As, Bs, acc);

  const int t = threadIdx.x;
  const int lane = t & 63, wv = t >> 6;
  const int l15 = lane & 15, quad = lane >> 4;
  const int wr = (wv >> 1) << 6, wc = (wv & 1) << 6;
  const float scale = (z==0) ? 0.125f : 1.f;
  const bool rope = (z<2);
  const int h = (n0 + wc) >> 6;          // one head per wave half-tile
  bf16_t* Oz = P.O[z];
  const bf16_t* Bz = P.Bi[z];
  float bvals[4];
  #pragma unroll
  for (int b=0;b<4;b++) bvals[b] = (float)Bz[h*64 + b*16 + l15];
  #pragma unroll
  for (int a=0;a<4;a++) {
    #pragma unroll
    for (int r=0;r<4;r++) {
      int row = m0 + wr + a*16 + quad*4 + r;
      int bb = row >> 11, spos = row & (SS-1);
      float vals[4];
      #pragma unroll
      for (int b=0;b<4;b++) vals[b] = (acc[a][b][r] + bvals[b]) * scale;
      if (rope) {
        float tv = tpos[row];
        #pragma unroll
        for (int b=0;b<2;b++) {
          int j = b*16 + l15;                   // freq index in [0,32)
          float inv = __expf(-(float)j * (9.210340371976184f/32.f));
          float ang = tv * inv;
          float sn = __sinf(ang), cs = __cosf(ang);
          float x1 = vals[b], x2 = vals[b+2];
          vals[b]   = x1*cs - x2*sn;
          vals[b+2] = x2*cs + x1*sn;
        }
      }
      bf16_t* dst = Oz + ((size_t)(bb*HH + h)*SS + spos)*DHH;
      #pragma unroll
      for (int b=0;b<4;b++) dst[b*16 + l15] = (bf16_t)vals[b];
    }
  }
}

// ---------------------------------------------------------------------------
// Fused FFN1+FFN3, BK=64 swizzled: g1 = silu(h0@W1) * (h0@W3).
// ---------------------------------------------------------------------------
__global__ __launch_bounds__(256) void gemm_ffn13(const bf16_t* __restrict__ A,
                                                  const bf16_t* __restrict__ B1T,
                                                  const bf16_t* __restrict__ B3T,
                                                  bf16_t* __restrict__ g1) {
  const int m0 = blockIdx.x*128, n0 = blockIdx.y*128;
  const int t = threadIdx.x;
  const int lane = t & 63, wv = t >> 6;
  const int l15 = lane & 15, quad = lane >> 4;
  const int wr = (wv >> 1) << 6, wc = (wv & 1) << 6;
  const int rsub = lane >> 3, pch = lane & 7;
  const int sch = pch ^ rsub;
  const int sx = l15 & 7;
  __shared__ bf16_t As[128*64];
  __shared__ bf16_t B1s[128*64];
  __shared__ bf16_t B3s[128*64];
  f32x4_t acc1[4][4], acc3[4][4];
  #pragma unroll
  for (int a=0;a<4;a++)
    #pragma unroll
    for (int b=0;b<4;b++) {
      acc1[a][b] = (f32x4_t){0.f,0.f,0.f,0.f};
      acc3[a][b] = (f32x4_t){0.f,0.f,0.f,0.f};
    }
  const size_t abase = (size_t)(m0 + wv*32 + rsub)*EE + sch*8;
  const size_t bbase = (size_t)(n0 + wv*32 + rsub)*EE + sch*8;
  bf16_t* lA  = As  + (wv*32)*64;
  bf16_t* lB1 = B1s + (wv*32)*64;
  bf16_t* lB3 = B3s + (wv*32)*64;
  for (int k0 = 0; k0 < EE; k0 += 64) {
    __syncthreads();
    #pragma unroll
    for (int j=0;j<4;j++) {
      gload16(A   + abase + (size_t)(j*8)*EE + k0, lA  + j*8*64);
      gload16(B1T + bbase + (size_t)(j*8)*EE + k0, lB1 + j*8*64);
      gload16(B3T + bbase + (size_t)(j*8)*EE + k0, lB3 + j*8*64);
    }
    __syncthreads();
    #pragma unroll
    for (int c=0;c<2;c++) {
      bf16x8_t af[4], b1f[4], b3f[4];
      #pragma unroll
      for (int a=0;a<4;a++)
        af[a] = *(const bf16x8_t*)&As[(wr + a*16 + l15)*64 + ((c*4+quad)^sx)*8];
      #pragma unroll
      for (int b=0;b<4;b++) {
        b1f[b] = *(const bf16x8_t*)&B1s[(wc + b*16 + l15)*64 + ((c*4+quad)^sx)*8];
        b3f[b] = *(const bf16x8_t*)&B3s[(wc + b*16 + l15)*64 + ((c*4+quad)^sx)*8];
      }
      #pragma unroll
      for (int a=0;a<4;a++)
        #pragma unroll
        for (int b=0;b<4;b++) {
          acc1[a][b] = __builtin_amdgcn_mfma_f32_16x16x32_bf16(af[a], b1f[b], acc1[a][b], 0,0,0);
          acc3[a][b] = __builtin_amdgcn_mfma_f32_16x16x32_bf16(af[a], b3f[b], acc3[a][b], 0,0,0);
        }
    }
  }
  #pragma unroll
  for (int a=0;a<4;a++)
    #pragma unroll
    for (int r=0;r<4;r++) {
      int row = m0 + wr + a*16 + quad*4 + r;
      #pragma unroll
      for (int b=0;b<4;b++) {
        float a1 = acc1[a][b][r];
        float sil = a1 / (1.f + __expf(-a1));
        g1[(size_t)row*FFN + n0 + wc + b*16 + l15] = (bf16_t)(sil * acc3[a][b][r]);
      }
    }
}

// ---------------------------------------------------------------------------
// FFN down, split-K=4: partial z covers K in [z*768,(z+1)*768) -> Pz (fp32).
// ---------------------------------------------------------------------------
struct Ffn2Out { float* p[4]; };

__global__ __launch_bounds__(256) void gemm_ffn2(const bf16_t* __restrict__ A,
                                                 const bf16_t* __restrict__ BT,
                                                 Ffn2Out O) {
  const int m0 = blockIdx.x*128, n0 = blockIdx.y*128;
  const int kz = blockIdx.z;
  __shared__ bf16_t As[128*64];
  __shared__ bf16_t Bs[128*64];
  f32x4_t acc[4][4];
  #pragma unroll
  for (int a=0;a<4;a++)
    #pragma unroll
    for (int b=0;b<4;b++) acc[a][b] = (f32x4_t){0.f,0.f,0.f,0.f};
  gemm128_core(A, BT, FFN, FFN, kz*768, (kz+1)*768, m0, n0, As, Bs, acc);
  const int t = threadIdx.x;
  const int lane = t & 63, wv = t >> 6;
  const int l15 = lane & 15, quad = lane >> 4;
  const int wr = (wv >> 1) << 6, wc = (wv & 1) << 6;
  float* C = O.p[kz];
  #pragma unroll
  for (int a=0;a<4;a++)
    #pragma unroll
    for (int r=0;r<4;r++) {
      int row = m0 + wr + a*16 + quad*4 + r;
      #pragma unroll
      for (int b=0;b<4;b++)
        C[(size_t)row*EE + n0 + wc + b*16 + l15] = acc[a][b][r];
    }
}

// ---------------------------------------------------------------------------
// gq projection (16 rows/batch).
// ---------------------------------------------------------------------------
__global__ __launch_bounds__(64) void qg_kernel(const bf16_t* __restrict__ x,
                                                const bf16_t* __restrict__ WqgT,
                                                const bf16_t* __restrict__ bqg,
                                                float* __restrict__ qgb) {
  int g = blockIdx.x, h = blockIdx.y, b = blockIdx.z;
  int d = threadIdx.x;
  __shared__ float xs[EE];
  for (int i=d; i<EE; i+=64) xs[i] = (float)x[((size_t)b*SS + g)*EE + i];
  __syncthreads();
  float acc = 0.f;
  const bf16_t* wrow = WqgT + (size_t)(h*64+d)*EE;
  for (int k=0;k<EE;k++) acc += xs[k] * (float)wrow[k];
  acc = (acc + (float)bqg[h*64+d]) * 0.125f;
  qgb[((size_t)(b*HH+h)*GG + g)*DHH + d] = acc;
}

// ---------------------------------------------------------------------------
// Band (sliding-window) attention + global-key columns, MFMA.
// ---------------------------------------------------------------------------
__global__ __launch_bounds__(256) void band_kernel(const bf16_t* __restrict__ qb,
                                                   const bf16_t* __restrict__ kb,
                                                   const bf16_t* __restrict__ vb,
                                                   const int* __restrict__ flags,
                                                   float* __restrict__ attn) {
  const int p0 = blockIdx.x*64;
  const int h = blockIdx.y, b = blockIdx.z;
  const int t = threadIdx.x;
  const int wv = t>>6, lane = t&63;
  const int l15 = lane & 15, quad = lane >> 4;
  const size_t bh = (size_t)(b*HH+h);
  const bf16_t* kbh = kb + bh*SS*DHH;
  const bf16_t* vbh = vb + bh*SS*DHH;
  const int* fl = flags + b*SS;
  const int q0 = p0 + wv*16;

  __shared__ bf16_t Vt[64*72];          // [dh][key]
  __shared__ bf16_t Pw[4][16*72];       // per-wave P [q][key]

  const bf16_t* qrow = qb + (bh*SS + q0 + l15)*DHH;
  bf16x8_t qa0 = *(const bf16x8_t*)(qrow + quad*8);
  bf16x8_t qa1 = *(const bf16x8_t*)(qrow + 32 + quad*8);

  f32x4_t o[4];
  #pragma unroll
  for (int i=0;i<4;i++) o[i] = (f32x4_t){0.f,0.f,0.f,0.f};
  float lsum[4] = {0.f,0.f,0.f,0.f};
  bf16_t* P = Pw[wv];

  for (int unit=0; unit<10; unit++) {
    const int kb0 = (unit<9) ? (p0 - 256 + unit*64) : 0;
    __syncthreads();
    {
      int kp  = (t & 31)*2;
      int dh0 = (t >> 5)*8;
      int k1 = kb0 + kp, k2 = kb0 + kp + 1;
      int kc1 = min(max(k1,0),SS-1), kc2 = min(max(k2,0),SS-1);
      bf16x8_t v1 = *(const bf16x8_t*)(vbh + (size_t)kc1*DHH + dh0);
      bf16x8_t v2 = *(const bf16x8_t*)(vbh + (size_t)kc2*DHH + dh0);
      #pragma unroll
      for (int i=0;i<8;i++) {
        union { unsigned u; bf16_t hh[2]; } pk;
        pk.hh[0] = v1[i]; pk.hh[1] = v2[i];
        *(unsigned*)&Vt[(dh0+i)*72 + kp] = pk.u;
      }
    }
    __syncthreads();
    const int nsub = (unit<9) ? 4 : 1;
    for (int sub=0; sub<4; sub++) {
      if (sub < nsub) {
        int kpos = kb0 + sub*16 + l15;
        int kc = min(max(kpos,0),SS-1);
        const bf16_t* krow = kbh + (size_t)kc*DHH;
        bf16x8_t kf0 = *(const bf16x8_t*)(krow + quad*8);
        bf16x8_t kf1 = *(const bf16x8_t*)(krow + 32 + quad*8);
        f32x4_t s = (f32x4_t){0.f,0.f,0.f,0.f};
        s = __builtin_amdgcn_mfma_f32_16x16x32_bf16(qa0, kf0, s, 0,0,0);
        s = __builtin_amdgcn_mfma_f32_16x16x32_bf16(qa1, kf1, s, 0,0,0);
        bool drop = false;
        if (unit<9) drop = (kpos<0) || (kpos>=SS) || (((fl[kc]>>2)&1)!=0);
        #pragma unroll
        for (int r=0;r<4;r++) {
          float e;
          if (unit==9) {
            e = __expf(s[r]);
          } else {
            int dj = kpos - (q0 + quad*4 + r);
            bool valid = (dj>=-256) && (dj<=256) && (!drop);
            e = valid ? __expf(s[r]) : 0.f;
          }
          lsum[r] += e;
          P[(quad*4+r)*72 + sub*16 + l15] = (bf16_t)e;
        }
      } else {
        #pragma unroll
        for (int r=0;r<4;r++) P[(quad*4+r)*72 + sub*16 + l15] = (bf16_t)0.f;
      }
    }
    #pragma unroll
    for (int chunk=0; chunk<2; chunk++) {
      bf16x8_t pf = *(const bf16x8_t*)&P[l15*72 + chunk*32 + quad*8];
      #pragma unroll
      for (int nt=0; nt<4; nt++) {
        bf16x8_t vf = *(const bf16x8_t*)&Vt[(nt*16+l15)*72 + chunk*32 + quad*8];
        o[nt] = __builtin_amdgcn_mfma_f32_16x16x32_bf16(pf, vf, o[nt], 0,0,0);
      }
    }
  }
  #pragma unroll
  for (int r=0;r<4;r++) {
    float s = lsum[r];
    s += __shfl_xor(s,1); s += __shfl_xor(s,2);
    s += __shfl_xor(s,4); s += __shfl_xor(s,8);
    lsum[r] = s;
  }
  #pragma unroll
  for (int r=0;r<4;r++) {
    int q = q0 + quad*4 + r;
    int masked = fl[q] & 1;
    float inv = masked ? 0.f : 1.f/lsum[r];
    float* dst = attn + ((size_t)(b*SS+q))*EE + h*64 + l15;
    #pragma unroll
    for (int nt=0; nt<4; nt++) dst[nt*16] = o[nt][r]*inv;
  }
}

// ---------------------------------------------------------------------------
// Global attention, key-split partials + finalize.
// ---------------------------------------------------------------------------
__global__ __launch_bounds__(256) void gattn_part(const float* __restrict__ qgb,
                                                  const bf16_t* __restrict__ kgb,
                                                  const bf16_t* __restrict__ vgb,
                                                  const int* __restrict__ flags,
                                                  float* __restrict__ go,
                                                  float* __restrict__ gl) {
  const int kbase = blockIdx.x*128;
  const int h = blockIdx.y, b = blockIdx.z;
  const int t = threadIdx.x;
  __shared__ float gqs[16*68];
  __shared__ float Ks[64*68];
  __shared__ float Vs[64*68];
  __shared__ float es[16*64];
  const size_t bh = (size_t)(b*HH+h);
  #pragma unroll
  for (int j=0;j<4;j++) {
    int idx = t + j*256;
    int g = idx>>6, d = idx&63;
    gqs[g*68+d] = qgb[(bh*GG + g)*DHH + d];
  }
  float accv[4] = {0.f,0.f,0.f,0.f};
  float lpart = 0.f;
  const int gs = t>>4, kslot = t&15;
  const int dp = t&63, grp = t>>6;
  const bf16_t* kb_ = kgb + bh*SS*DHH;
  const bf16_t* vb_ = vgb + bh*SS*DHH;
  const int* fl = flags + b*SS;
  for (int tile=0; tile<2; tile++) {
    int k0 = kbase + tile*64;
    __syncthreads();
    {
      int row = t>>2, seg = t&3;
      const bf16_t* sk = kb_ + (size_t)(k0+row)*DHH + seg*16;
      const bf16_t* sv = vb_ + (size_t)(k0+row)*DHH + seg*16;
      bf16x8_t k1 = *(const bf16x8_t*)sk;
      bf16x8_t k2 = *(const bf16x8_t*)(sk+8);
      bf16x8_t v1 = *(const bf16x8_t*)sv;
      bf16x8_t v2 = *(const bf16x8_t*)(sv+8);
      #pragma unroll
      for (int i=0;i<8;i++) {
        Ks[row*68 + seg*16 + i]     = (float)k1[i];
        Ks[row*68 + seg*16 + 8 + i] = (float)k2[i];
        Vs[row*68 + seg*16 + i]     = (float)v1[i];
        Vs[row*68 + seg*16 + 8 + i] = (float)v2[i];
      }
    }
    __syncthreads();
    #pragma unroll
    for (int j=0;j<4;j++) {
      int key = kslot + 16*j;
      const float* gq = &gqs[gs*68];
      const float* kr = &Ks[key*68];
      float s = 0.f;
      #pragma unroll
      for (int d4=0; d4<64; d4+=4) {
        float4 a = *(const float4*)(gq + d4);
        float4 kk = *(const float4*)(kr + d4);
        s += a.x*kk.x + a.y*kk.y + a.z*kk.z + a.w*kk.w;
      }
      int msk = fl[k0+key] & 1;
      float e = msk ? 0.f : __expf(s);
      es[gs*64+key] = e;
      lpart += e;
    }
    __syncthreads();
    #pragma unroll
    for (int g=0; g<4; g++) {
      int gg = grp*4+g;
      float a = accv[g];
      for (int key=0;key<64;key++) a += es[gg*64+key]*Vs[key*68+dp];
      accv[g] = a;
    }
  }
  __syncthreads();
  es[gs*64 + kslot] = lpart;
  __syncthreads();
  if (t < 16) {
    float s = 0.f;
    for (int j=0;j<16;j++) s += es[t*64+j];
    atomicAdd(&gl[bh*16 + t], s);
  }
  #pragma unroll
  for (int g=0; g<4; g++)
    atomicAdd(&go[(bh*16 + grp*4+g)*64 + dp], accv[g]);
}

__global__ __launch_bounds__(256) void gattn_fin(const float* __restrict__ go,
                                                 const float* __restrict__ gl,
                                                 float* __restrict__ attn) {
  int idx = blockIdx.x*256 + threadIdx.x;        // < B*H*16*64 = 24576
  int dp = idx & 63;
  int g  = (idx >> 6) & 15;
  int h  = (idx >> 10) % HH;
  int b  = idx / (1024*HH);
  attn[((size_t)b*SS + g)*EE + h*64 + dp] = go[idx] / gl[idx>>6];
}

// ---------------------------------------------------------------------------
// Residual add + LayerNorm. B-side = sum of up to 4 fp32 partials.
// ---------------------------------------------------------------------------
__global__ __launch_bounds__(256) void addln_kernel(const bf16_t* __restrict__ Abf,
                                                    const float* __restrict__ Af,
                                                    const float* __restrict__ B0,
                                                    const float* __restrict__ B1,
                                                    const float* __restrict__ B2,
                                                    const float* __restrict__ B3,
                                                    const bf16_t* __restrict__ gw,
                                                    const bf16_t* __restrict__ bw,
                                                    float* __restrict__ outf,
                                                    bf16_t* __restrict__ outb,
                                                    const int* __restrict__ flagp) {
  int r = blockIdx.x, t = threadIdx.x;
  int lane = t&63, wv = t>>6;
  float v[3]; float sum=0.f, ss=0.f;
  #pragma unroll
  for (int j=0;j<3;j++) {
    int idx = t + j*256;
    size_t gi = (size_t)r*EE+idx;
    float a = Abf ? (float)Abf[gi] : Af[gi];
    float val = a + B0[gi];
    if (B1) val += B1[gi] + B2[gi] + B3[gi];
    v[j] = val; sum += val; ss += val*val;
  }
  #pragma unroll
  for (int off=32; off>=1; off>>=1) {
    sum += __shfl_xor(sum, off);
    ss  += __shfl_xor(ss, off);
  }
  __shared__ float s1[4], s2[4];
  if (lane==0) { s1[wv]=sum; s2[wv]=ss; }
  __syncthreads();
  sum = s1[0]+s1[1]+s1[2]+s1[3];
  ss  = s2[0]+s2[1]+s2[2]+s2[3];
  float mean = sum * (1.f/(float)EE);
  float var  = ss * (1.f/(float)EE) - mean*mean;
  float rstd = rsqrtf(var + 1e-5f);
  bool wantb, wantf;
  if (flagp) { bool isb = (*flagp)!=0; wantb = isb; wantf = !isb; }
  else { wantb = (outb!=nullptr); wantf = (outf!=nullptr); }
  #pragma unroll
  for (int j=0;j<3;j++) {
    int idx = t + j*256;
    float o = (v[j]-mean)*rstd*(float)gw[idx] + (float)bw[idx];
    if (wantf) outf[(size_t)r*EE+idx] = o;
    if (wantb) outb[(size_t)r*EE+idx] = (bf16_t)o;
  }
}

// ---------------------------------------------------------------------------
extern "C" void kernel_launch(void* const* d_in, const int* in_sizes, int n_in,
                              void* d_out, int out_size, void* d_ws, size_t ws_size,
                              hipStream_t stream) {
  const void* x_r    = d_in[0];
  const int* am      = (const int*)d_in[1];
  const int* gm      = (const int*)d_in[2];
  (void)in_sizes; (void)n_in; (void)out_size; (void)ws_size;

  char* ws = (char*)d_ws;
  size_t off = 0;
  auto alloc = [&](size_t bytes) -> void* {
    void* p = ws + off;
    off += (bytes + 255) & ~(size_t)255;
    return p;
  };
  // canonical bf16 tensors (weights transposed to [N][K])
  bf16_t* xc    = (bf16_t*)alloc((size_t)MM*EE*2);
  bf16_t* WT[6]; bf16_t* bc[6];
  for (int i=0;i<6;i++) { WT[i] = (bf16_t*)alloc((size_t)EE*EE*2); bc[i] = (bf16_t*)alloc(EE*2); }
  bf16_t* lnc[4];
  for (int i=0;i<4;i++) lnc[i] = (bf16_t*)alloc(EE*2);
  bf16_t* W1T = (bf16_t*)alloc((size_t)EE*FFN*2);
  bf16_t* W3T = (bf16_t*)alloc((size_t)EE*FFN*2);
  bf16_t* W2T = (bf16_t*)alloc((size_t)FFN*EE*2);
  // intermediates
  const size_t NBHSD = (size_t)BB_*HH*SS*DHH;
  bf16_t* qb    = (bf16_t*)alloc(NBHSD*2);
  bf16_t* kb    = (bf16_t*)alloc(NBHSD*2);
  bf16_t* vb    = (bf16_t*)alloc(NBHSD*2);
  bf16_t* kgb   = (bf16_t*)alloc(NBHSD*2);
  bf16_t* vgb   = (bf16_t*)alloc(NBHSD*2);
  float* qgb   = (float*)alloc((size_t)BB_*HH*GG*DHH*4);
  float* attn  = (float*)alloc((size_t)MM*EE*4);    // reused as ffn2 partial 0
  float* h0f   = (float*)alloc((size_t)MM*EE*4);
  bf16_t* h0b  = (bf16_t*)alloc((size_t)MM*EE*2);
  bf16_t* g1   = (bf16_t*)alloc((size_t)MM*FFN*2);
  float* p3    = (float*)alloc((size_t)MM*EE*4);    // ffn2 partial 3
  float* go    = (float*)alloc((size_t)BB_*HH*GG*DHH*4);  // 24576 f32
  float* gl    = (float*)alloc((size_t)BB_*HH*GG*4);      // 384 f32 (contiguous)
  float* tposb = (float*)alloc((size_t)BB_*SS*4);
  int*   flagb = (int*)alloc((size_t)BB_*SS*4);
  int*   dflag = (int*)alloc(256);
  // ffn2 partials 1/2 alias the q/k/v region (dead before ffn2; 25.2MB <= 31.5MB)
  float* p1 = (float*)qb;
  float* p2 = (float*)qb + (size_t)MM*EE;

  // 0. dtype detect on Wq
  detect_kernel<<<1, 64, 0, stream>>>((const unsigned int*)d_in[3], dflag);

  // 1. canonicalize x + biases + ln
  CanonP CP;
  const void* csrc[11] = { x_r, d_in[4], d_in[6], d_in[8], d_in[10], d_in[12], d_in[14],
                           d_in[15], d_in[16], d_in[17], d_in[18] };
  bf16_t* cdst[11] = { xc, bc[0], bc[1], bc[2], bc[3], bc[4], bc[5],
                       lnc[0], lnc[1], lnc[2], lnc[3] };
  for (int i=0;i<11;i++) { CP.src[i]=csrc[i]; CP.dst[i]=cdst[i]; }
  canon_kernel<<<3081, 256, 0, stream>>>(CP, dflag);

  // 2. transpose-canonicalize weights
  TP6 T6;
  const int wi[6] = {3,5,7,9,11,13};                 // Wq Wk Wv Wqg Wkg Wvg
  for (int i=0;i<6;i++) { T6.s[i]=d_in[wi[i]]; T6.d[i]=WT[i]; }
  trans_kernel<<<dim3(24,24,6), 256, 0, stream>>>(T6, EE, EE, dflag);
  TP6 TF; TF.s[0]=d_in[19]; TF.d[0]=W1T; TF.s[1]=d_in[20]; TF.d[1]=W3T;
  for (int i=2;i<6;i++) { TF.s[i]=d_in[19]; TF.d[i]=W1T; }
  trans_kernel<<<dim3(96,24,2), 256, 0, stream>>>(TF, EE, FFN, dflag);
  TP6 T2; T2.s[0]=d_in[21]; T2.d[0]=W2T;
  for (int i=1;i<6;i++) { T2.s[i]=d_in[21]; T2.d[i]=W2T; }
  trans_kernel<<<dim3(24,96,1), 256, 0, stream>>>(T2, FFN, EE, dflag);

  // 3. zero global-attn accumulators (go+gl contiguous: 24960 floats)
  zero_kernel<<<98, 256, 0, stream>>>(go, 24960);

  // 4. mask flags + rope positions
  flags_kernel<<<BB_, 256, 0, stream>>>(am, gm, tposb, flagb);

  // 5. fused projections (q,k,v,kg,vg)
  ProjParams P;
  P.W[0]=WT[0]; P.Bi[0]=bc[0]; P.O[0]=qb;
  P.W[1]=WT[1]; P.Bi[1]=bc[1]; P.O[1]=kb;
  P.W[2]=WT[2]; P.Bi[2]=bc[2]; P.O[2]=vb;
  P.W[3]=WT[4]; P.Bi[3]=bc[4]; P.O[3]=kgb;   // Wkg
  P.W[4]=WT[5]; P.Bi[4]=bc[5]; P.O[4]=vgb;   // Wvg
  proj_kernel<<<dim3(MM/128, EE/128, 5), 256, 0, stream>>>(xc, P, tposb);

  // 6. gq (first G rows per batch)
  qg_kernel<<<dim3(GG, HH, BB_), 64, 0, stream>>>(xc, WT[3], bc[3], qgb);

  // 7. band + global-column attention -> attn
  band_kernel<<<dim3(SS/64, HH, BB_), 256, 0, stream>>>(qb, kb, vb, flagb, attn);

  // 8. global-attention rows (key-split partials + finalize)
  gattn_part<<<dim3(SS/128, HH, BB_), 256, 0, stream>>>(qgb, kgb, vgb, flagb, go, gl);
  gattn_fin<<<96, 256, 0, stream>>>(go, gl, attn);

  // 9. h0 = LN(x + attn)
  addln_kernel<<<MM, 256, 0, stream>>>(xc, nullptr, attn, nullptr, nullptr, nullptr,
                                       lnc[0], lnc[1], h0f, h0b, nullptr);

  // 10. FFN: fused gate (BK=64 swizzled), then split-K down-proj
  gemm_ffn13<<<dim3(MM/128, FFN/128), 256, 0, stream>>>(h0b, W1T, W3T, g1);
  Ffn2Out FO; FO.p[0]=attn; FO.p[1]=p1; FO.p[2]=p2; FO.p[3]=p3;
  gemm_ffn2<<<dim3(MM/128, EE/128, 4), 256, 0, stream>>>(g1, W2T, FO);

  // 11. out = LN(h0 + sum of ffn partials) -> fp32 or bf16 per detected dtype
  addln_kernel<<<MM, 256, 0, stream>>>(nullptr, h0f, attn, p1, p2, p3,
                                       lnc[2], lnc[3],
                                       (float*)d_out, (bf16_t*)d_out, dflag);
}

// Round 8
// 392.307 us; speedup vs baseline: 1.0798x; 1.0155x over previous
//
#include <hip/hip_runtime.h>

// Longformer block, MI355X. B=2 S=2048 E=768 H=12 DH=64 W=256 G=16 FF=3072.
// R7: un-fuse ffn13 -> ffn1 + ffn3. Fused kernel's dual accumulator (128 acc
// regs + 148 arch regs ~ 276 unified) capped occupancy at 1 wave/SIMD (10.3%
// measured) -- no TLP to hide the K-step barrier drain. Single-acc kernels
// run 3 waves/SIMD. Also: qg vectorized (was scalar strided), gattn_fin
// folded into first addln.

#define BB_ 2
#define SS 2048
#define EE 768
#define HH 12
#define DHH 64
#define GG 16
#define FFN 3072
#define MM (BB_*SS)   // 4096

typedef __bf16 bf16_t;
typedef __bf16 bf16x8_t __attribute__((ext_vector_type(8)));
typedef float f32x4_t __attribute__((ext_vector_type(4)));

// async global->LDS, 16B per lane; lds dest = wave-uniform base + lane*16
__device__ inline void gload16(const void* g, void* l) {
  __builtin_amdgcn_global_load_lds((const __attribute__((address_space(1))) void*)g,
                                   (__attribute__((address_space(3))) void*)l, 16, 0, 0);
}

// ---------------------------------------------------------------------------
// dtype detector (fp32 vs bf16 inputs).
// ---------------------------------------------------------------------------
__global__ __launch_bounds__(64) void detect_kernel(const unsigned int* __restrict__ w,
                                                    int* __restrict__ flag) {
  int cnt = 0;
  for (int i = threadIdx.x; i < 1024; i += 64) {
    unsigned e = (w[i] >> 7) & 0xFF;
    cnt += (e >= 100 && e <= 144) ? 1 : 0;
  }
  for (int off = 32; off; off >>= 1) cnt += __shfl_xor(cnt, off);
  if (threadIdx.x == 0) flag[0] = (cnt > 512) ? 1 : 0;   // 1 = inputs are bf16
}

// ---------------------------------------------------------------------------
// canonicalize x + biases + ln params into bf16.
// ---------------------------------------------------------------------------
struct CanonP { const void* src[11]; bf16_t* dst[11]; };

__global__ __launch_bounds__(256) void canon_kernel(CanonP P, const int* __restrict__ flag) {
  constexpr int ns[11] = {3145728, 768,768,768,768,768,768, 768,768,768,768};
  int idx4 = (blockIdx.x*256 + threadIdx.x)*4;
  const bool isb = flag[0] != 0;
  int off = 0, seg = -1, loc = 0;
  #pragma unroll
  for (int i=0;i<11;i++) {
    if (seg < 0 && idx4 < off + ns[i]) { seg = i; loc = idx4 - off; }
    off += ns[i];
  }
  if (seg < 0) return;
  const void* s = P.src[seg];
  bf16_t* d = P.dst[seg];
  if (isb) {
    *(uint2*)&d[loc] = *(const uint2*)((const unsigned short*)s + loc);
  } else {
    float4 v = *(const float4*)((const float*)s + loc);
    d[loc+0] = (bf16_t)v.x; d[loc+1] = (bf16_t)v.y;
    d[loc+2] = (bf16_t)v.z; d[loc+3] = (bf16_t)v.w;
  }
}

// ---------------------------------------------------------------------------
// transpose + canonicalize: src (R x C) -> dst (C x R, bf16)
// ---------------------------------------------------------------------------
struct TP6 { const void* s[6]; bf16_t* d[6]; };

__global__ __launch_bounds__(256) void trans_kernel(TP6 P, int R, int C,
                                                    const int* __restrict__ flag) {
  const int z = blockIdx.z;
  const void* src = P.s[z]; bf16_t* dst = P.d[z];
  const bool isb = flag[0] != 0;
  __shared__ bf16_t tile[32][33];
  int tx = threadIdx.x & 31, ty = threadIdx.x >> 5;
  int r0 = blockIdx.y*32, c0 = blockIdx.x*32;
  #pragma unroll
  for (int i=0;i<4;i++) {
    int rr = ty + i*8;
    size_t si = (size_t)(r0+rr)*C + c0 + tx;
    tile[rr][tx] = isb ? ((const bf16_t*)src)[si] : (bf16_t)((const float*)src)[si];
  }
  __syncthreads();
  #pragma unroll
  for (int i=0;i<4;i++) {
    int cc = ty + i*8;
    dst[(size_t)(c0+cc)*R + r0 + tx] = tile[tx][cc];
  }
}

__global__ __launch_bounds__(256) void zero_kernel(float* __restrict__ p, int n) {
  int i = blockIdx.x*256 + threadIdx.x;
  if (i < n) p[i] = 0.f;
}

// ---------------------------------------------------------------------------
// flags + rope positions.
// ---------------------------------------------------------------------------
__global__ __launch_bounds__(256) void flags_kernel(const int* __restrict__ am,
                                                    const int* __restrict__ gm,
                                                    float* __restrict__ tpos,
                                                    int* __restrict__ flags) {
  int b = blockIdx.x;
  int t = threadIdx.x;
  int lane = t & 63, wv = t >> 6;
  int base = b*SS + t*8;
  int mg[8]; int isg[8]; int loc = 0;
  for (int i=0;i<8;i++) {
    int a = am[base+i], g = gm[base+i];
    int merged = a*(g+1);
    mg[i] = merged;
    isg[i] = (merged==2) ? 1 : 0;
    loc += isg[i];
  }
  int x = loc;
  for (int off=1; off<64; off<<=1) {
    int y = __shfl_up(x, off);
    if (lane >= off) x += y;
  }
  __shared__ int wtot[4];
  if (lane==63) wtot[wv] = x;
  __syncthreads();
  int prev = 0;
  for (int w=0; w<wv; w++) prev += wtot[w];
  int run = prev + x - loc;
  for (int i=0;i<8;i++) {
    run += isg[i];
    int masked = (mg[i]==0) ? 1 : 0;
    int glob   = (mg[i]==2) ? 1 : 0;
    int rem    = (mg[i]!=1) ? 1 : 0;
    tpos[base+i]  = masked ? 0.f : (float)run;
    flags[base+i] = masked | (glob<<1) | (rem<<2);
  }
}

// ---------------------------------------------------------------------------
// 128x128-tile BK=64 GEMM core with XOR chunk swizzle.
// LDS row r (stride 64 elems), 16B-chunk position p holds global chunk p^(r&7).
// ---------------------------------------------------------------------------
__device__ inline void gemm128_core(const bf16_t* __restrict__ A,
                                    const bf16_t* __restrict__ BT,
                                    int ldA, int ldB, int kbeg, int kend,
                                    int m0, int n0,
                                    bf16_t* As, bf16_t* Bs,
                                    f32x4_t (&acc)[4][4]) {
  const int t = threadIdx.x;
  const int lane = t & 63, wv = t >> 6;
  const int l15 = lane & 15, quad = lane >> 4;
  const int wr = (wv >> 1) << 6, wc = (wv & 1) << 6;
  const int rsub = lane >> 3, pch = lane & 7;    // staging row-sub / chunk pos
  const int sch = pch ^ rsub;                    // swizzled source chunk
  const size_t abase = (size_t)(m0 + wv*32 + rsub)*ldA + sch*8;
  const size_t bbase = (size_t)(n0 + wv*32 + rsub)*ldB + sch*8;
  const int sx = l15 & 7;                        // read-side swizzle
  bf16_t* lA = As + (wv*32)*64;
  bf16_t* lB = Bs + (wv*32)*64;
  for (int k0 = kbeg; k0 < kend; k0 += 64) {
    __syncthreads();
    #pragma unroll
    for (int j=0;j<4;j++) {
      gload16(A + abase + (size_t)(j*8)*ldA + k0, lA + j*8*64);
      gload16(BT + bbase + (size_t)(j*8)*ldB + k0, lB + j*8*64);
    }
    __syncthreads();
    #pragma unroll
    for (int c=0;c<2;c++) {
      bf16x8_t af[4], bfr[4];
      #pragma unroll
      for (int a=0;a<4;a++)
        af[a] = *(const bf16x8_t*)&As[(wr + a*16 + l15)*64 + ((c*4+quad)^sx)*8];
      #pragma unroll
      for (int b=0;b<4;b++)
        bfr[b] = *(const bf16x8_t*)&Bs[(wc + b*16 + l15)*64 + ((c*4+quad)^sx)*8];
      #pragma unroll
      for (int a=0;a<4;a++)
        #pragma unroll
        for (int b=0;b<4;b++)
          acc[a][b] = __builtin_amdgcn_mfma_f32_16x16x32_bf16(af[a], bfr[b], acc[a][b], 0,0,0);
    }
  }
}

// ---------------------------------------------------------------------------
// Fused QKV(+global KV) projection. z: 0=q(scale+rope) 1=k(rope) 2=v 3=kg 4=vg.
// ---------------------------------------------------------------------------
struct ProjParams {
  const bf16_t* W[5];   // transposed [N][K]
  const bf16_t* Bi[5];
  bf16_t* O[5];
};

__global__ __launch_bounds__(256) void proj_kernel(const bf16_t* __restrict__ x,
                                                   ProjParams P,
                                                   const float* __restrict__ tpos) {
  const int m0 = blockIdx.x*128, n0 = blockIdx.y*128;
  const int z  = blockIdx.z;
  __shared__ bf16_t As[128*64];
  __shared__ bf16_t Bs[128*64];
  f32x4_t acc[4][4];
  #pragma unroll
  for (int a=0;a<4;a++)
    #pragma unroll
    for (int b=0;b<4;b++) acc[a][b] = (f32x4_t){0.f,0.f,0.f,0.f};
  gemm128_core(x, P.W[z], EE, EE, 0, EE, m0, n0, As, Bs, acc);

  const int t = threadIdx.x;
  const int lane = t & 63, wv = t >> 6;
  const int l15 = lane & 15, quad = lane >> 4;
  const int wr = (wv >> 1) << 6, wc = (wv & 1) << 6;
  const float scale = (z==0) ? 0.125f : 1.f;
  const bool rope = (z<2);
  const int h = (n0 + wc) >> 6;          // one head per wave half-tile
  bf16_t* Oz = P.O[z];
  const bf16_t* Bz = P.Bi[z];
  float bvals[4];
  #pragma unroll
  for (int b=0;b<4;b++) bvals[b] = (float)Bz[h*64 + b*16 + l15];
  #pragma unroll
  for (int a=0;a<4;a++) {
    #pragma unroll
    for (int r=0;r<4;r++) {
      int row = m0 + wr + a*16 + quad*4 + r;
      int bb = row >> 11, spos = row & (SS-1);
      float vals[4];
      #pragma unroll
      for (int b=0;b<4;b++) vals[b] = (acc[a][b][r] + bvals[b]) * scale;
      if (rope) {
        float tv = tpos[row];
        #pragma unroll
        for (int b=0;b<2;b++) {
          int j = b*16 + l15;                   // freq index in [0,32)
          float inv = __expf(-(float)j * (9.210340371976184f/32.f));
          float ang = tv * inv;
          float sn = __sinf(ang), cs = __cosf(ang);
          float x1 = vals[b], x2 = vals[b+2];
          vals[b]   = x1*cs - x2*sn;
          vals[b+2] = x2*cs + x1*sn;
        }
      }
      bf16_t* dst = Oz + ((size_t)(bb*HH + h)*SS + spos)*DHH;
      #pragma unroll
      for (int b=0;b<4;b++) dst[b*16 + l15] = (bf16_t)vals[b];
    }
  }
}

// ---------------------------------------------------------------------------
// FFN1: t1 = h0 @ W1 (bf16). Single accumulator -> 3 waves/SIMD.
// ---------------------------------------------------------------------------
__global__ __launch_bounds__(256) void gemm_ffn1(const bf16_t* __restrict__ A,
                                                 const bf16_t* __restrict__ BT,
                                                 bf16_t* __restrict__ t1) {
  const int m0 = blockIdx.x*128, n0 = blockIdx.y*128;
  __shared__ bf16_t As[128*64];
  __shared__ bf16_t Bs[128*64];
  f32x4_t acc[4][4];
  #pragma unroll
  for (int a=0;a<4;a++)
    #pragma unroll
    for (int b=0;b<4;b++) acc[a][b] = (f32x4_t){0.f,0.f,0.f,0.f};
  gemm128_core(A, BT, EE, EE, 0, EE, m0, n0, As, Bs, acc);
  const int t = threadIdx.x;
  const int lane = t & 63, wv = t >> 6;
  const int l15 = lane & 15, quad = lane >> 4;
  const int wr = (wv >> 1) << 6, wc = (wv & 1) << 6;
  #pragma unroll
  for (int a=0;a<4;a++)
    #pragma unroll
    for (int r=0;r<4;r++) {
      int row = m0 + wr + a*16 + quad*4 + r;
      #pragma unroll
      for (int b=0;b<4;b++)
        t1[(size_t)row*FFN + n0 + wc + b*16 + l15] = (bf16_t)acc[a][b][r];
    }
}

// ---------------------------------------------------------------------------
// FFN3 + gate: g1 = silu(t1) * (h0 @ W3). Single accumulator.
// ---------------------------------------------------------------------------
__global__ __launch_bounds__(256) void gemm_ffn3(const bf16_t* __restrict__ A,
                                                 const bf16_t* __restrict__ BT,
                                                 const bf16_t* __restrict__ t1,
                                                 bf16_t* __restrict__ g1) {
  const int m0 = blockIdx.x*128, n0 = blockIdx.y*128;
  __shared__ bf16_t As[128*64];
  __shared__ bf16_t Bs[128*64];
  f32x4_t acc[4][4];
  #pragma unroll
  for (int a=0;a<4;a++)
    #pragma unroll
    for (int b=0;b<4;b++) acc[a][b] = (f32x4_t){0.f,0.f,0.f,0.f};
  gemm128_core(A, BT, EE, EE, 0, EE, m0, n0, As, Bs, acc);
  const int t = threadIdx.x;
  const int lane = t & 63, wv = t >> 6;
  const int l15 = lane & 15, quad = lane >> 4;
  const int wr = (wv >> 1) << 6, wc = (wv & 1) << 6;
  #pragma unroll
  for (int a=0;a<4;a++)
    #pragma unroll
    for (int r=0;r<4;r++) {
      int row = m0 + wr + a*16 + quad*4 + r;
      #pragma unroll
      for (int b=0;b<4;b++) {
        size_t idx = (size_t)row*FFN + n0 + wc + b*16 + l15;
        float a1 = (float)t1[idx];
        float sil = a1 / (1.f + __expf(-a1));
        g1[idx] = (bf16_t)(sil * acc[a][b][r]);
      }
    }
}

// ---------------------------------------------------------------------------
// FFN down, split-K=4: partial z covers K in [z*768,(z+1)*768) -> Pz (fp32).
// ---------------------------------------------------------------------------
struct Ffn2Out { float* p[4]; };

__global__ __launch_bounds__(256) void gemm_ffn2(const bf16_t* __restrict__ A,
                                                 const bf16_t* __restrict__ BT,
                                                 Ffn2Out O) {
  const int m0 = blockIdx.x*128, n0 = blockIdx.y*128;
  const int kz = blockIdx.z;
  __shared__ bf16_t As[128*64];
  __shared__ bf16_t Bs[128*64];
  f32x4_t acc[4][4];
  #pragma unroll
  for (int a=0;a<4;a++)
    #pragma unroll
    for (int b=0;b<4;b++) acc[a][b] = (f32x4_t){0.f,0.f,0.f,0.f};
  gemm128_core(A, BT, FFN, FFN, kz*768, (kz+1)*768, m0, n0, As, Bs, acc);
  const int t = threadIdx.x;
  const int lane = t & 63, wv = t >> 6;
  const int l15 = lane & 15, quad = lane >> 4;
  const int wr = (wv >> 1) << 6, wc = (wv & 1) << 6;
  float* C = O.p[kz];
  #pragma unroll
  for (int a=0;a<4;a++)
    #pragma unroll
    for (int r=0;r<4;r++) {
      int row = m0 + wr + a*16 + quad*4 + r;
      #pragma unroll
      for (int b=0;b<4;b++)
        C[(size_t)row*EE + n0 + wc + b*16 + l15] = acc[a][b][r];
    }
}

// ---------------------------------------------------------------------------
// gq projection (16 rows/batch), vectorized weight loads.
// ---------------------------------------------------------------------------
__global__ __launch_bounds__(64) void qg_kernel(const bf16_t* __restrict__ x,
                                                const bf16_t* __restrict__ WqgT,
                                                const bf16_t* __restrict__ bqg,
                                                float* __restrict__ qgb) {
  int g = blockIdx.x, h = blockIdx.y, b = blockIdx.z;
  int d = threadIdx.x;
  __shared__ float xs[EE];
  for (int i=d; i<EE; i+=64) xs[i] = (float)x[((size_t)b*SS + g)*EE + i];
  __syncthreads();
  float acc = 0.f;
  const bf16_t* wrow = WqgT + (size_t)(h*64+d)*EE;
  #pragma unroll 4
  for (int k=0;k<EE;k+=8) {
    bf16x8_t w8 = *(const bf16x8_t*)(wrow + k);
    #pragma unroll
    for (int i=0;i<8;i++) acc += xs[k+i] * (float)w8[i];
  }
  acc = (acc + (float)bqg[h*64+d]) * 0.125f;
  qgb[((size_t)(b*HH+h)*GG + g)*DHH + d] = acc;
}

// ---------------------------------------------------------------------------
// Band (sliding-window) attention + global-key columns, MFMA.
// ---------------------------------------------------------------------------
__global__ __launch_bounds__(256) void band_kernel(const bf16_t* __restrict__ qb,
                                                   const bf16_t* __restrict__ kb,
                                                   const bf16_t* __restrict__ vb,
                                                   const int* __restrict__ flags,
                                                   float* __restrict__ attn) {
  const int p0 = blockIdx.x*64;
  const int h = blockIdx.y, b = blockIdx.z;
  const int t = threadIdx.x;
  const int wv = t>>6, lane = t&63;
  const int l15 = lane & 15, quad = lane >> 4;
  const size_t bh = (size_t)(b*HH+h);
  const bf16_t* kbh = kb + bh*SS*DHH;
  const bf16_t* vbh = vb + bh*SS*DHH;
  const int* fl = flags + b*SS;
  const int q0 = p0 + wv*16;

  __shared__ bf16_t Vt[64*72];          // [dh][key]
  __shared__ bf16_t Pw[4][16*72];       // per-wave P [q][key]

  const bf16_t* qrow = qb + (bh*SS + q0 + l15)*DHH;
  bf16x8_t qa0 = *(const bf16x8_t*)(qrow + quad*8);
  bf16x8_t qa1 = *(const bf16x8_t*)(qrow + 32 + quad*8);

  f32x4_t o[4];
  #pragma unroll
  for (int i=0;i<4;i++) o[i] = (f32x4_t){0.f,0.f,0.f,0.f};
  float lsum[4] = {0.f,0.f,0.f,0.f};
  bf16_t* P = Pw[wv];

  for (int unit=0; unit<10; unit++) {
    const int kb0 = (unit<9) ? (p0 - 256 + unit*64) : 0;
    __syncthreads();
    {
      int kp  = (t & 31)*2;
      int dh0 = (t >> 5)*8;
      int k1 = kb0 + kp, k2 = kb0 + kp + 1;
      int kc1 = min(max(k1,0),SS-1), kc2 = min(max(k2,0),SS-1);
      bf16x8_t v1 = *(const bf16x8_t*)(vbh + (size_t)kc1*DHH + dh0);
      bf16x8_t v2 = *(const bf16x8_t*)(vbh + (size_t)kc2*DHH + dh0);
      #pragma unroll
      for (int i=0;i<8;i++) {
        union { unsigned u; bf16_t hh[2]; } pk;
        pk.hh[0] = v1[i]; pk.hh[1] = v2[i];
        *(unsigned*)&Vt[(dh0+i)*72 + kp] = pk.u;
      }
    }
    __syncthreads();
    const int nsub = (unit<9) ? 4 : 1;
    for (int sub=0; sub<4; sub++) {
      if (sub < nsub) {
        int kpos = kb0 + sub*16 + l15;
        int kc = min(max(kpos,0),SS-1);
        const bf16_t* krow = kbh + (size_t)kc*DHH;
        bf16x8_t kf0 = *(const bf16x8_t*)(krow + quad*8);
        bf16x8_t kf1 = *(const bf16x8_t*)(krow + 32 + quad*8);
        f32x4_t s = (f32x4_t){0.f,0.f,0.f,0.f};
        s = __builtin_amdgcn_mfma_f32_16x16x32_bf16(qa0, kf0, s, 0,0,0);
        s = __builtin_amdgcn_mfma_f32_16x16x32_bf16(qa1, kf1, s, 0,0,0);
        bool drop = false;
        if (unit<9) drop = (kpos<0) || (kpos>=SS) || (((fl[kc]>>2)&1)!=0);
        #pragma unroll
        for (int r=0;r<4;r++) {
          float e;
          if (unit==9) {
            e = __expf(s[r]);
          } else {
            int dj = kpos - (q0 + quad*4 + r);
            bool valid = (dj>=-256) && (dj<=256) && (!drop);
            e = valid ? __expf(s[r]) : 0.f;
          }
          lsum[r] += e;
          P[(quad*4+r)*72 + sub*16 + l15] = (bf16_t)e;
        }
      } else {
        #pragma unroll
        for (int r=0;r<4;r++) P[(quad*4+r)*72 + sub*16 + l15] = (bf16_t)0.f;
      }
    }
    #pragma unroll
    for (int chunk=0; chunk<2; chunk++) {
      bf16x8_t pf = *(const bf16x8_t*)&P[l15*72 + chunk*32 + quad*8];
      #pragma unroll
      for (int nt=0; nt<4; nt++) {
        bf16x8_t vf = *(const bf16x8_t*)&Vt[(nt*16+l15)*72 + chunk*32 + quad*8];
        o[nt] = __builtin_amdgcn_mfma_f32_16x16x32_bf16(pf, vf, o[nt], 0,0,0);
      }
    }
  }
  #pragma unroll
  for (int r=0;r<4;r++) {
    float s = lsum[r];
    s += __shfl_xor(s,1); s += __shfl_xor(s,2);
    s += __shfl_xor(s,4); s += __shfl_xor(s,8);
    lsum[r] = s;
  }
  #pragma unroll
  for (int r=0;r<4;r++) {
    int q = q0 + quad*4 + r;
    int masked = fl[q] & 1;
    float inv = masked ? 0.f : 1.f/lsum[r];
    float* dst = attn + ((size_t)(b*SS+q))*EE + h*64 + l15;
    #pragma unroll
    for (int nt=0; nt<4; nt++) dst[nt*16] = o[nt][r]*inv;
  }
}

// ---------------------------------------------------------------------------
// Global attention, key-split partials (finalize folded into addln).
// ---------------------------------------------------------------------------
__global__ __launch_bounds__(256) void gattn_part(const float* __restrict__ qgb,
                                                  const bf16_t* __restrict__ kgb,
                                                  const bf16_t* __restrict__ vgb,
                                                  const int* __restrict__ flags,
                                                  float* __restrict__ go,
                                                  float* __restrict__ gl) {
  const int kbase = blockIdx.x*128;
  const int h = blockIdx.y, b = blockIdx.z;
  const int t = threadIdx.x;
  __shared__ float gqs[16*68];
  __shared__ float Ks[64*68];
  __shared__ float Vs[64*68];
  __shared__ float es[16*64];
  const size_t bh = (size_t)(b*HH+h);
  #pragma unroll
  for (int j=0;j<4;j++) {
    int idx = t + j*256;
    int g = idx>>6, d = idx&63;
    gqs[g*68+d] = qgb[(bh*GG + g)*DHH + d];
  }
  float accv[4] = {0.f,0.f,0.f,0.f};
  float lpart = 0.f;
  const int gs = t>>4, kslot = t&15;
  const int dp = t&63, grp = t>>6;
  const bf16_t* kb_ = kgb + bh*SS*DHH;
  const bf16_t* vb_ = vgb + bh*SS*DHH;
  const int* fl = flags + b*SS;
  for (int tile=0; tile<2; tile++) {
    int k0 = kbase + tile*64;
    __syncthreads();
    {
      int row = t>>2, seg = t&3;
      const bf16_t* sk = kb_ + (size_t)(k0+row)*DHH + seg*16;
      const bf16_t* sv = vb_ + (size_t)(k0+row)*DHH + seg*16;
      bf16x8_t k1 = *(const bf16x8_t*)sk;
      bf16x8_t k2 = *(const bf16x8_t*)(sk+8);
      bf16x8_t v1 = *(const bf16x8_t*)sv;
      bf16x8_t v2 = *(const bf16x8_t*)(sv+8);
      #pragma unroll
      for (int i=0;i<8;i++) {
        Ks[row*68 + seg*16 + i]     = (float)k1[i];
        Ks[row*68 + seg*16 + 8 + i] = (float)k2[i];
        Vs[row*68 + seg*16 + i]     = (float)v1[i];
        Vs[row*68 + seg*16 + 8 + i] = (float)v2[i];
      }
    }
    __syncthreads();
    #pragma unroll
    for (int j=0;j<4;j++) {
      int key = kslot + 16*j;
      const float* gq = &gqs[gs*68];
      const float* kr = &Ks[key*68];
      float s = 0.f;
      #pragma unroll
      for (int d4=0; d4<64; d4+=4) {
        float4 a = *(const float4*)(gq + d4);
        float4 kk = *(const float4*)(kr + d4);
        s += a.x*kk.x + a.y*kk.y + a.z*kk.z + a.w*kk.w;
      }
      int msk = fl[k0+key] & 1;
      float e = msk ? 0.f : __expf(s);
      es[gs*64+key] = e;
      lpart += e;
    }
    __syncthreads();
    #pragma unroll
    for (int g=0; g<4; g++) {
      int gg = grp*4+g;
      float a = accv[g];
      for (int key=0;key<64;key++) a += es[gg*64+key]*Vs[key*68+dp];
      accv[g] = a;
    }
  }
  __syncthreads();
  es[gs*64 + kslot] = lpart;
  __syncthreads();
  if (t < 16) {
    float s = 0.f;
    for (int j=0;j<16;j++) s += es[t*64+j];
    atomicAdd(&gl[bh*16 + t], s);
  }
  #pragma unroll
  for (int g=0; g<4; g++)
    atomicAdd(&go[(bh*16 + grp*4+g)*64 + dp], accv[g]);
}

// ---------------------------------------------------------------------------
// Residual add + LayerNorm. B-side = sum of up to 4 fp32 partials.
// If gof!=nullptr, rows with (r mod S) < G take the attention value from
// go/gl (global-attention overwrite) instead of B0.
// ---------------------------------------------------------------------------
__global__ __launch_bounds__(256) void addln_kernel(const bf16_t* __restrict__ Abf,
                                                    const float* __restrict__ Af,
                                                    const float* __restrict__ B0,
                                                    const float* __restrict__ B1,
                                                    const float* __restrict__ B2,
                                                    const float* __restrict__ B3,
                                                    const float* __restrict__ gof,
                                                    const float* __restrict__ glf,
                                                    const bf16_t* __restrict__ gw,
                                                    const bf16_t* __restrict__ bw,
                                                    float* __restrict__ outf,
                                                    bf16_t* __restrict__ outb,
                                                    const int* __restrict__ flagp) {
  int r = blockIdx.x, t = threadIdx.x;
  int lane = t&63, wv = t>>6;
  int spos = r & (SS-1), bb = r >> 11;
  bool isglob = (gof != nullptr) && (spos < GG);
  float v[3]; float sum=0.f, ss=0.f;
  #pragma unroll
  for (int j=0;j<3;j++) {
    int idx = t + j*256;
    size_t gi = (size_t)r*EE+idx;
    float a = Abf ? (float)Abf[gi] : Af[gi];
    float bv;
    if (isglob) {
      int hh = idx >> 6, dp = idx & 63;
      int slot = (bb*HH + hh)*GG + spos;
      bv = gof[(size_t)slot*DHH + dp] / glf[slot];
    } else {
      bv = B0[gi];
    }
    float val = a + bv;
    if (B1) val += B1[gi] + B2[gi] + B3[gi];
    v[j] = val; sum += val; ss += val*val;
  }
  #pragma unroll
  for (int off=32; off>=1; off>>=1) {
    sum += __shfl_xor(sum, off);
    ss  += __shfl_xor(ss, off);
  }
  __shared__ float s1[4], s2[4];
  if (lane==0) { s1[wv]=sum; s2[wv]=ss; }
  __syncthreads();
  sum = s1[0]+s1[1]+s1[2]+s1[3];
  ss  = s2[0]+s2[1]+s2[2]+s2[3];
  float mean = sum * (1.f/(float)EE);
  float var  = ss * (1.f/(float)EE) - mean*mean;
  float rstd = rsqrtf(var + 1e-5f);
  bool wantb, wantf;
  if (flagp) { bool isb = (*flagp)!=0; wantb = isb; wantf = !isb; }
  else { wantb = (outb!=nullptr); wantf = (outf!=nullptr); }
  #pragma unroll
  for (int j=0;j<3;j++) {
    int idx = t + j*256;
    float o = (v[j]-mean)*rstd*(float)gw[idx] + (float)bw[idx];
    if (wantf) outf[(size_t)r*EE+idx] = o;
    if (wantb) outb[(size_t)r*EE+idx] = (bf16_t)o;
  }
}

// ---------------------------------------------------------------------------
extern "C" void kernel_launch(void* const* d_in, const int* in_sizes, int n_in,
                              void* d_out, int out_size, void* d_ws, size_t ws_size,
                              hipStream_t stream) {
  const void* x_r    = d_in[0];
  const int* am      = (const int*)d_in[1];
  const int* gm      = (const int*)d_in[2];
  (void)in_sizes; (void)n_in; (void)out_size; (void)ws_size;

  char* ws = (char*)d_ws;
  size_t off = 0;
  auto alloc = [&](size_t bytes) -> void* {
    void* p = ws + off;
    off += (bytes + 255) & ~(size_t)255;
    return p;
  };
  // canonical bf16 tensors (weights transposed to [N][K])
  bf16_t* xc    = (bf16_t*)alloc((size_t)MM*EE*2);
  bf16_t* WT[6]; bf16_t* bc[6];
  for (int i=0;i<6;i++) { WT[i] = (bf16_t*)alloc((size_t)EE*EE*2); bc[i] = (bf16_t*)alloc(EE*2); }
  bf16_t* lnc[4];
  for (int i=0;i<4;i++) lnc[i] = (bf16_t*)alloc(EE*2);
  bf16_t* W1T = (bf16_t*)alloc((size_t)EE*FFN*2);
  bf16_t* W3T = (bf16_t*)alloc((size_t)EE*FFN*2);
  bf16_t* W2T = (bf16_t*)alloc((size_t)FFN*EE*2);
  // intermediates
  const size_t NBHSD = (size_t)BB_*HH*SS*DHH;
  bf16_t* qb    = (bf16_t*)alloc(NBHSD*2);
  bf16_t* kb    = (bf16_t*)alloc(NBHSD*2);
  bf16_t* vb    = (bf16_t*)alloc(NBHSD*2);
  bf16_t* kgb   = (bf16_t*)alloc(NBHSD*2);
  bf16_t* vgb   = (bf16_t*)alloc(NBHSD*2);
  float* qgb   = (float*)alloc((size_t)BB_*HH*GG*DHH*4);
  float* attn  = (float*)alloc((size_t)MM*EE*4);    // reused as ffn2 partial 0
  float* h0f   = (float*)alloc((size_t)MM*EE*4);
  bf16_t* h0b  = (bf16_t*)alloc((size_t)MM*EE*2);
  bf16_t* g1   = (bf16_t*)alloc((size_t)MM*FFN*2);
  float* p3    = (float*)alloc((size_t)MM*EE*4);    // ffn2 partial 3
  float* go    = (float*)alloc((size_t)BB_*HH*GG*DHH*4);  // 24576 f32
  float* gl    = (float*)alloc((size_t)BB_*HH*GG*4);      // 384 f32 (contiguous)
  float* tposb = (float*)alloc((size_t)BB_*SS*4);
  int*   flagb = (int*)alloc((size_t)BB_*SS*4);
  int*   dflag = (int*)alloc(256);
  // t1 aliases qb..kgb (25.2MB, dead after attention); ffn2 partials 1/2
  // overwrite the same region afterwards (t1 dead once g1 is written).
  bf16_t* t1 = qb;
  float* p1 = (float*)qb;
  float* p2 = (float*)qb + (size_t)MM*EE;

  // 0. dtype detect on Wq
  detect_kernel<<<1, 64, 0, stream>>>((const unsigned int*)d_in[3], dflag);

  // 1. canonicalize x + biases + ln
  CanonP CP;
  const void* csrc[11] = { x_r, d_in[4], d_in[6], d_in[8], d_in[10], d_in[12], d_in[14],
                           d_in[15], d_in[16], d_in[17], d_in[18] };
  bf16_t* cdst[11] = { xc, bc[0], bc[1], bc[2], bc[3], bc[4], bc[5],
                       lnc[0], lnc[1], lnc[2], lnc[3] };
  for (int i=0;i<11;i++) { CP.src[i]=csrc[i]; CP.dst[i]=cdst[i]; }
  canon_kernel<<<3081, 256, 0, stream>>>(CP, dflag);

  // 2. transpose-canonicalize weights
  TP6 T6;
  const int wi[6] = {3,5,7,9,11,13};                 // Wq Wk Wv Wqg Wkg Wvg
  for (int i=0;i<6;i++) { T6.s[i]=d_in[wi[i]]; T6.d[i]=WT[i]; }
  trans_kernel<<<dim3(24,24,6), 256, 0, stream>>>(T6, EE, EE, dflag);
  TP6 TF; TF.s[0]=d_in[19]; TF.d[0]=W1T; TF.s[1]=d_in[20]; TF.d[1]=W3T;
  for (int i=2;i<6;i++) { TF.s[i]=d_in[19]; TF.d[i]=W1T; }
  trans_kernel<<<dim3(96,24,2), 256, 0, stream>>>(TF, EE, FFN, dflag);
  TP6 T2; T2.s[0]=d_in[21]; T2.d[0]=W2T;
  for (int i=1;i<6;i++) { T2.s[i]=d_in[21]; T2.d[i]=W2T; }
  trans_kernel<<<dim3(24,96,1), 256, 0, stream>>>(T2, FFN, EE, dflag);

  // 3. zero global-attn accumulators (go+gl contiguous: 24960 floats)
  zero_kernel<<<98, 256, 0, stream>>>(go, 24960);

  // 4. mask flags + rope positions
  flags_kernel<<<BB_, 256, 0, stream>>>(am, gm, tposb, flagb);

  // 5. fused projections (q,k,v,kg,vg)
  ProjParams P;
  P.W[0]=WT[0]; P.Bi[0]=bc[0]; P.O[0]=qb;
  P.W[1]=WT[1]; P.Bi[1]=bc[1]; P.O[1]=kb;
  P.W[2]=WT[2]; P.Bi[2]=bc[2]; P.O[2]=vb;
  P.W[3]=WT[4]; P.Bi[3]=bc[4]; P.O[3]=kgb;   // Wkg
  P.W[4]=WT[5]; P.Bi[4]=bc[5]; P.O[4]=vgb;   // Wvg
  proj_kernel<<<dim3(MM/128, EE/128, 5), 256, 0, stream>>>(xc, P, tposb);

  // 6. gq (first G rows per batch)
  qg_kernel<<<dim3(GG, HH, BB_), 64, 0, stream>>>(xc, WT[3], bc[3], qgb);

  // 7. band + global-column attention -> attn
  band_kernel<<<dim3(SS/64, HH, BB_), 256, 0, stream>>>(qb, kb, vb, flagb, attn);

  // 8. global-attention rows (key-split partials; finalize folded into addln)
  gattn_part<<<dim3(SS/128, HH, BB_), 256, 0, stream>>>(qgb, kgb, vgb, flagb, go, gl);

  // 9. h0 = LN(x + attn)   (rows < G take go/gl)
  addln_kernel<<<MM, 256, 0, stream>>>(xc, nullptr, attn, nullptr, nullptr, nullptr,
                                       go, gl, lnc[0], lnc[1], h0f, h0b, nullptr);

  // 10. FFN: ffn1 -> t1 (aliases dead q/k/v), ffn3 fused gate -> g1,
  //     then split-K down-proj (partials p1/p2 overwrite t1 region)
  gemm_ffn1<<<dim3(MM/128, FFN/128), 256, 0, stream>>>(h0b, W1T, t1);
  gemm_ffn3<<<dim3(MM/128, FFN/128), 256, 0, stream>>>(h0b, W3T, t1, g1);
  Ffn2Out FO; FO.p[0]=attn; FO.p[1]=p1; FO.p[2]=p2; FO.p[3]=p3;
  gemm_ffn2<<<dim3(MM/128, EE/128, 4), 256, 0, stream>>>(g1, W2T, FO);

  // 11. out = LN(h0 + sum of ffn partials) -> fp32 or bf16 per detected dtype
  addln_kernel<<<MM, 256, 0, stream>>>(nullptr, h0f, attn, p1, p2, p3,
                                       nullptr, nullptr, lnc[2], lnc[3],
                                       (float*)d_out, (bf16_t*)d_out, dflag);
}